// Round 1
// baseline (3424.926 us; speedup 1.0000x reference)
//
#include <hip/hip_runtime.h>
#include <hip/hip_bf16.h>
#include <math.h>

// Problem constants
constexpr int kB   = 2;
constexpr int kS   = 2048;
constexpr int kD   = 1024;
constexpr int kFFN = 4096;
constexpr int kM   = kB * kS;      // 4096 tokens
constexpr int kH   = 8;
constexpr int kDH  = 128;
constexpr int kNC  = 64;           // scan chunks
constexpr int kT   = kS / kNC;     // 32 steps per chunk

__device__ __forceinline__ float sigf(float x) { return 1.0f / (1.0f + __expf(-x)); }

// ---------------- RMSNorm: one row (D=1024) per block of 256 ----------------
__global__ __launch_bounds__(256) void rmsnorm_k(const float* __restrict__ x,
                                                 const float* __restrict__ w,
                                                 float* __restrict__ o)
{
    __shared__ float red[4];
    const int row = blockIdx.x;
    const int t = threadIdx.x;
    float4 v = ((const float4*)(x + (size_t)row * kD))[t];
    float ss = v.x*v.x + v.y*v.y + v.z*v.z + v.w*v.w;
    #pragma unroll
    for (int m = 32; m; m >>= 1) ss += __shfl_xor(ss, m);
    if ((t & 63) == 0) red[t >> 6] = ss;
    __syncthreads();
    float tot = red[0] + red[1] + red[2] + red[3];
    float r = rsqrtf(tot * (1.0f / (float)kD) + 1e-6f);
    float4 wv = ((const float4*)w)[t];
    float4 ov;
    ov.x = v.x * r * wv.x; ov.y = v.y * r * wv.y;
    ov.z = v.z * r * wv.z; ov.w = v.w * r * wv.w;
    ((float4*)(o + (size_t)row * kD))[t] = ov;
}

// ---------------- Routing: one wave per row; logits = xn @ gate_w (D x 4) ----
__global__ __launch_bounds__(64) void routing_k(const float* __restrict__ xn,
                                                const float* __restrict__ gw,
                                                float* __restrict__ wts,
                                                int* __restrict__ idx)
{
    const int row = blockIdx.x;
    const int lane = threadIdx.x;
    const float* xr = xn + (size_t)row * kD;
    float acc0 = 0, acc1 = 0, acc2 = 0, acc3 = 0;
    for (int d = lane; d < kD; d += 64) {
        float xv = xr[d];
        float4 g = ((const float4*)gw)[d];
        acc0 = fmaf(xv, g.x, acc0);
        acc1 = fmaf(xv, g.y, acc1);
        acc2 = fmaf(xv, g.z, acc2);
        acc3 = fmaf(xv, g.w, acc3);
    }
    #pragma unroll
    for (int m = 32; m; m >>= 1) {
        acc0 += __shfl_xor(acc0, m);
        acc1 += __shfl_xor(acc1, m);
        acc2 += __shfl_xor(acc2, m);
        acc3 += __shfl_xor(acc3, m);
    }
    if (lane == 0) {
        float a[4] = {acc0, acc1, acc2, acc3};
        int i0 = 0; float v0 = a[0];
        #pragma unroll
        for (int e = 1; e < 4; ++e) if (a[e] > v0) { v0 = a[e]; i0 = e; }
        int i1 = -1; float v1 = -INFINITY;
        #pragma unroll
        for (int e = 0; e < 4; ++e) if (e != i0 && a[e] > v1) { v1 = a[e]; i1 = e; }
        float e1 = __expf(v1 - v0);
        float dn = 1.0f + e1;
        wts[row * 2 + 0] = 1.0f / dn;
        wts[row * 2 + 1] = e1 / dn;
        idx[row * 2 + 0] = i0;
        idx[row * 2 + 1] = i1;
    }
}

// ---------------- f32 GEMM: C[M,N] = A[M,K] @ B[K,N] (+bias)(+res)(dual+silu) -
// BM=128, BN=64, BK=16, 256 threads, 8x4 per thread.
template<bool BIAS, bool RES, bool DUAL>
__global__ __launch_bounds__(256) void gemm_k(const float* __restrict__ A,
                                              const float* __restrict__ Bmat,
                                              const float* __restrict__ B2,
                                              const float* __restrict__ bias,
                                              const float* __restrict__ res,
                                              float* __restrict__ C,
                                              int N, int K)
{
    constexpr int BM = 128, BN = 64, BK = 16;
    __shared__ float As[BK][BM];
    __shared__ float Bs[BK][BN];
    __shared__ float Bs2[DUAL ? BK : 1][DUAL ? BN : 1];

    const int tid = threadIdx.x;
    const int bm = blockIdx.y * BM;
    const int bn = blockIdx.x * BN;
    const int tx = tid & 15;           // col group (4 cols)
    const int ty = tid >> 4;           // row group (8 rows)
    const int arow = tid >> 2;         // 0..63
    const int ak4  = (tid & 3) * 4;    // 0,4,8,12
    const int brow = tid >> 4;         // 0..15
    const int bc4  = (tid & 15) * 4;   // 0..60

    float acc[8][4] = {};
    float acc2[DUAL ? 8 : 1][DUAL ? 4 : 1] = {};

    for (int k0 = 0; k0 < K; k0 += BK) {
        #pragma unroll
        for (int r = 0; r < 2; ++r) {
            int row = arow + r * 64;
            float4 av = *(const float4*)(A + (size_t)(bm + row) * K + k0 + ak4);
            As[ak4 + 0][row] = av.x;
            As[ak4 + 1][row] = av.y;
            As[ak4 + 2][row] = av.z;
            As[ak4 + 3][row] = av.w;
        }
        *(float4*)&Bs[brow][bc4] =
            *(const float4*)(Bmat + (size_t)(k0 + brow) * N + bn + bc4);
        if constexpr (DUAL) {
            *(float4*)&Bs2[brow][bc4] =
                *(const float4*)(B2 + (size_t)(k0 + brow) * N + bn + bc4);
        }
        __syncthreads();
        #pragma unroll
        for (int kk = 0; kk < BK; ++kk) {
            const float4 a0 = *(const float4*)&As[kk][ty * 8];
            const float4 a1 = *(const float4*)&As[kk][ty * 8 + 4];
            const float4 b0 = *(const float4*)&Bs[kk][tx * 4];
            const float av[8] = {a0.x, a0.y, a0.z, a0.w, a1.x, a1.y, a1.z, a1.w};
            const float bv[4] = {b0.x, b0.y, b0.z, b0.w};
            #pragma unroll
            for (int i = 0; i < 8; ++i)
                #pragma unroll
                for (int j = 0; j < 4; ++j)
                    acc[i][j] = fmaf(av[i], bv[j], acc[i][j]);
            if constexpr (DUAL) {
                const float4 c0 = *(const float4*)&Bs2[kk][tx * 4];
                const float cv[4] = {c0.x, c0.y, c0.z, c0.w};
                #pragma unroll
                for (int i = 0; i < 8; ++i)
                    #pragma unroll
                    for (int j = 0; j < 4; ++j)
                        acc2[i][j] = fmaf(av[i], cv[j], acc2[i][j]);
            }
        }
        __syncthreads();
    }

    #pragma unroll
    for (int i = 0; i < 8; ++i) {
        int row = bm + ty * 8 + i;
        size_t off = (size_t)row * N + bn + tx * 4;
        float o[4];
        #pragma unroll
        for (int j = 0; j < 4; ++j) {
            float val = acc[i][j];
            if constexpr (BIAS) val += bias[bn + tx * 4 + j];
            if constexpr (DUAL) val = val * sigf(val) * acc2[i][j];
            o[j] = val;
        }
        if constexpr (RES) {
            float4 rv = *(const float4*)(res + off);
            o[0] += rv.x; o[1] += rv.y; o[2] += rv.z; o[3] += rv.w;
        }
        float4 ov; ov.x = o[0]; ov.y = o[1]; ov.z = o[2]; ov.w = o[3];
        *(float4*)(C + off) = ov;
    }
}

// ---------------- minGRU chunked scan (3 phases), inline sigmoid/tanh --------
// phase 1: per (b, chunk, d): local products/partials
__global__ __launch_bounds__(256) void scan1_k(const float* __restrict__ g,
                                               const float* __restrict__ v,
                                               const float* __restrict__ dd,
                                               float* __restrict__ sumA,
                                               float* __restrict__ sumX)
{
    int i = blockIdx.x * 256 + threadIdx.x;      // [0, kB*kNC*kD)
    int d = i & (kD - 1);
    int c = (i >> 10) & (kNC - 1);
    int b = i >> 16;                             // /(kD*kNC)
    size_t base = ((size_t)b * kS + c * kT) * kD + d;
    float A = 1.0f, X = 0.0f;
    for (int t = 0; t < kT; ++t) {
        size_t ix = base + (size_t)t * kD;
        float xs = sigf(g[ix]) * tanhf(v[ix]);
        float a  = 0.001f + 0.998f * sigf(dd[ix]);
        A *= a;
        X = fmaf(a, X, xs);
    }
    sumA[c * (kB * kD) + b * kD + d] = A;
    sumX[c * (kB * kD) + b * kD + d] = X;
}

// phase 2: serial scan over chunk summaries per channel
__global__ __launch_bounds__(256) void scan2_k(const float* __restrict__ sumA,
                                               const float* __restrict__ sumX,
                                               float* __restrict__ carry)
{
    int bd = blockIdx.x * 256 + threadIdx.x;     // [0, kB*kD)
    float h = 0.0f;
    for (int c = 0; c < kNC; ++c) {
        carry[c * (kB * kD) + bd] = h;
        h = fmaf(sumA[c * (kB * kD) + bd], h, sumX[c * (kB * kD) + bd]);
    }
}

// phase 3: re-scan chunk with carry-in, write h
__global__ __launch_bounds__(256) void scan3_k(const float* __restrict__ g,
                                               const float* __restrict__ v,
                                               const float* __restrict__ dd,
                                               const float* __restrict__ carry,
                                               float* __restrict__ hout)
{
    int i = blockIdx.x * 256 + threadIdx.x;
    int d = i & (kD - 1);
    int c = (i >> 10) & (kNC - 1);
    int b = i >> 16;
    size_t base = ((size_t)b * kS + c * kT) * kD + d;
    float h = carry[c * (kB * kD) + b * kD + d];
    for (int t = 0; t < kT; ++t) {
        size_t ix = base + (size_t)t * kD;
        float xs = sigf(g[ix]) * tanhf(v[ix]);
        float a  = 0.001f + 0.998f * sigf(dd[ix]);
        h = fmaf(a, h, xs);
        hout[ix] = h;
    }
}

// ---------------- MoE mix: x1 = x + w0*eh[i0] + w1*eh[i1] --------------------
__global__ __launch_bounds__(256) void mix_k(const float* __restrict__ x,
                                             const float* __restrict__ eh,
                                             const float* __restrict__ wts,
                                             const int* __restrict__ idx,
                                             float* __restrict__ xo)
{
    size_t i = (size_t)blockIdx.x * 256 + threadIdx.x;  // float4 index
    int m = (int)(i >> 8);                               // / (kD/4)
    float w0 = wts[m * 2 + 0], w1 = wts[m * 2 + 1];
    int e0 = idx[m * 2 + 0], e1 = idx[m * 2 + 1];
    size_t MD4 = (size_t)kM * (kD / 4);
    float4 xv = ((const float4*)x)[i];
    float4 h0 = ((const float4*)eh)[(size_t)e0 * MD4 + i];
    float4 h1 = ((const float4*)eh)[(size_t)e1 * MD4 + i];
    float4 o;
    o.x = xv.x + w0 * h0.x + w1 * h1.x;
    o.y = xv.y + w0 * h0.y + w1 * h1.y;
    o.z = xv.z + w0 * h0.z + w1 * h1.z;
    o.w = xv.w + w0 * h0.w + w1 * h1.w;
    ((float4*)xo)[i] = o;
}

// ---------------- Sliding-window attention (WIN=128), 64-query tiles --------
// qkv layout: [b*S + s][3*D], q at col h*128+d, k at 1024+h*128+d, v at 2048+...
__global__ __launch_bounds__(256) void attn_k(const float* __restrict__ qkv,
                                              float* __restrict__ ao)
{
    constexpr int TQ = 64;
    constexpr int QP = 129;   // Q/K pitch (scalar reads, conflict-friendly)
    constexpr int VP = 132;   // V pitch (float4-aligned)
    constexpr int SP = 194;   // score pitch
    __shared__ float Qs[TQ][QP];
    __shared__ float Ks[TQ][QP];
    __shared__ float Vs[TQ][VP];
    __shared__ float Ss[TQ][SP];
    __shared__ float Ls[TQ];

    const int tid = threadIdx.x;
    const int q0 = blockIdx.x * TQ;
    const int hh = blockIdx.y;
    const int bb = blockIdx.z;
    const size_t rs = 3 * kD;
    const float* base = qkv + (size_t)bb * kS * rs + hh * kDH;
    const float scale = 0.08838834764831845f;   // 1/sqrt(128)

    // stage Q tile
    for (int f = tid; f < TQ * kDH / 4; f += 256) {
        int r = f >> 5, d4 = (f & 31) * 4;
        float4 v = *(const float4*)(base + (size_t)(q0 + r) * rs + d4);
        Qs[r][d4 + 0] = v.x; Qs[r][d4 + 1] = v.y;
        Qs[r][d4 + 2] = v.z; Qs[r][d4 + 3] = v.w;
    }

    const int kbase = q0 - 128;
    const int tx = tid & 15, ty = tid >> 4;

    // scores: 3 chunks of 64 keys
    for (int c = 0; c < 3; ++c) {
        int kb = kbase + c * 64;
        if (kb + 63 < 0) continue;   // block-uniform skip (fully out of range)
        for (int f = tid; f < 64 * kDH / 4; f += 256) {
            int r = f >> 5, d4 = (f & 31) * 4;
            int kg = kb + r; kg = kg < 0 ? 0 : kg;
            float4 v = *(const float4*)(base + (size_t)kg * rs + kD + d4);
            Ks[r][d4 + 0] = v.x; Ks[r][d4 + 1] = v.y;
            Ks[r][d4 + 2] = v.z; Ks[r][d4 + 3] = v.w;
        }
        __syncthreads();
        float sa[4][4] = {};
        #pragma unroll 4
        for (int d = 0; d < kDH; ++d) {
            float qv[4], kv[4];
            #pragma unroll
            for (int i = 0; i < 4; ++i) qv[i] = Qs[ty * 4 + i][d];
            #pragma unroll
            for (int j = 0; j < 4; ++j) kv[j] = Ks[tx * 4 + j][d];
            #pragma unroll
            for (int i = 0; i < 4; ++i)
                #pragma unroll
                for (int j = 0; j < 4; ++j)
                    sa[i][j] = fmaf(qv[i], kv[j], sa[i][j]);
        }
        #pragma unroll
        for (int i = 0; i < 4; ++i)
            #pragma unroll
            for (int j = 0; j < 4; ++j)
                Ss[ty * 4 + i][c * 64 + tx * 4 + j] = sa[i][j] * scale;
        __syncthreads();
    }

    // softmax: 4 threads per row; valid k in [max(q+1, 128-q0), q+128]
    {
        int q = tid >> 2, g = tid & 3;
        int klo = q + 1;
        int t2 = 128 - q0; if (t2 > klo) klo = t2;
        int khi = q + 128;
        float m = -INFINITY;
        for (int k = klo + g; k <= khi; k += 4) m = fmaxf(m, Ss[q][k]);
        m = fmaxf(m, __shfl_xor(m, 1));
        m = fmaxf(m, __shfl_xor(m, 2));
        float l = 0.0f;
        for (int k = g; k < 192; k += 4) {
            float p = 0.0f;
            if (k >= klo && k <= khi) p = __expf(Ss[q][k] - m);
            Ss[q][k] = p;
            l += p;
        }
        l += __shfl_xor(l, 1);
        l += __shfl_xor(l, 2);
        if (g == 0) Ls[q] = l;
    }
    __syncthreads();

    // PV: accumulate O[q][128] over 3 chunks
    float oa[4][8] = {};
    for (int c = 0; c < 3; ++c) {
        int kb = kbase + c * 64;
        if (kb + 63 < 0) continue;
        for (int f = tid; f < 64 * kDH / 4; f += 256) {
            int r = f >> 5, d4 = (f & 31) * 4;
            int kg = kb + r; kg = kg < 0 ? 0 : kg;
            float4 v = *(const float4*)(base + (size_t)kg * rs + 2 * kD + d4);
            *(float4*)&Vs[r][d4] = v;
        }
        __syncthreads();
        for (int k = 0; k < 64; ++k) {
            float p[4];
            #pragma unroll
            for (int i = 0; i < 4; ++i) p[i] = Ss[ty * 4 + i][c * 64 + k];
            const float4 v0 = *(const float4*)&Vs[k][tx * 8];
            const float4 v1 = *(const float4*)&Vs[k][tx * 8 + 4];
            const float vv[8] = {v0.x, v0.y, v0.z, v0.w, v1.x, v1.y, v1.z, v1.w};
            #pragma unroll
            for (int i = 0; i < 4; ++i)
                #pragma unroll
                for (int u = 0; u < 8; ++u)
                    oa[i][u] = fmaf(p[i], vv[u], oa[i][u]);
        }
        __syncthreads();
    }

    #pragma unroll
    for (int i = 0; i < 4; ++i) {
        int q = ty * 4 + i;
        float inv = 1.0f / Ls[q];
        float* orow = ao + ((size_t)bb * kS + q0 + q) * kD + hh * kDH + tx * 8;
        float4 o0, o1;
        o0.x = oa[i][0] * inv; o0.y = oa[i][1] * inv;
        o0.z = oa[i][2] * inv; o0.w = oa[i][3] * inv;
        o1.x = oa[i][4] * inv; o1.y = oa[i][5] * inv;
        o1.z = oa[i][6] * inv; o1.w = oa[i][7] * inv;
        *(float4*)orow = o0;
        *(float4*)(orow + 4) = o1;
    }
}

// ---------------------------------------------------------------------------
extern "C" void kernel_launch(void* const* d_in, const int* in_sizes, int n_in,
                              void* d_out, int out_size, void* d_ws, size_t ws_size,
                              hipStream_t stream)
{
    (void)in_sizes; (void)n_in; (void)out_size; (void)ws_size;

    const float* x          = (const float*)d_in[0];
    const float* rms_mix    = (const float*)d_in[1];
    const float* gate_w     = (const float*)d_in[2];
    const float* Wg         = (const float*)d_in[3];
    const float* bg         = (const float*)d_in[4];
    const float* Wv         = (const float*)d_in[5];
    const float* bv         = (const float*)d_in[6];
    const float* Wd         = (const float*)d_in[7];
    const float* bd         = (const float*)d_in[8];
    const float* rms_attn   = (const float*)d_in[9];
    const float* w_qkv      = (const float*)d_in[10];
    const float* w_attn_out = (const float*)d_in[11];
    const float* rms_ffn    = (const float*)d_in[12];
    const float* w_ffn_gate = (const float*)d_in[13];
    const float* w_ffn_up   = (const float*)d_in[14];
    const float* w_ffn_out  = (const float*)d_in[15];
    float* out = (float*)d_out;

    float* ws = (float*)d_ws;
    const size_t MD = (size_t)kM * kD;
    float* xn    = ws;                  // MD
    float* buf3  = xn + MD;             // 3*MD   (g,v,d  then qkv)
    float* eh    = buf3 + 3 * MD;       // 4*MD   (expert h / ao / ffn hidden)
    float* sumA  = eh + 4 * MD;         // kB*kD*kNC
    float* sumX  = sumA + kB * kD * kNC;
    float* carry = sumX + kB * kD * kNC;
    float* wts   = carry + kB * kD * kNC;   // 2*kM
    int*   tidx  = (int*)(wts + 2 * kM);    // 2*kM

    const dim3 blk(256);

    // 1) xn = rmsnorm(x, rms_mix)
    rmsnorm_k<<<kM, blk, 0, stream>>>(x, rms_mix, xn);

    // 2) routing (top-2 + softmax)
    routing_k<<<kM, dim3(64), 0, stream>>>(xn, gate_w, wts, tidx);

    // 3) experts
    const dim3 gD(kD / 64, kM / 128);
    const int scan_blocks = kB * kD * kNC / 256;
    for (int e = 0; e < 4; ++e) {
        const size_t wo = (size_t)e * kD * kD;
        gemm_k<true, false, false><<<gD, blk, 0, stream>>>(
            xn, Wg + wo, nullptr, bg + e * kD, nullptr, buf3, kD, kD);
        gemm_k<true, false, false><<<gD, blk, 0, stream>>>(
            xn, Wv + wo, nullptr, bv + e * kD, nullptr, buf3 + MD, kD, kD);
        gemm_k<true, false, false><<<gD, blk, 0, stream>>>(
            xn, Wd + wo, nullptr, bd + e * kD, nullptr, buf3 + 2 * MD, kD, kD);
        scan1_k<<<scan_blocks, blk, 0, stream>>>(buf3, buf3 + MD, buf3 + 2 * MD, sumA, sumX);
        scan2_k<<<kB * kD / 256, blk, 0, stream>>>(sumA, sumX, carry);
        scan3_k<<<scan_blocks, blk, 0, stream>>>(buf3, buf3 + MD, buf3 + 2 * MD, carry,
                                                 eh + (size_t)e * MD);
    }

    // 4) MoE mix -> out used as x1
    mix_k<<<(int)(MD / 1024), blk, 0, stream>>>(x, eh, wts, tidx, out);

    // 5) attention
    rmsnorm_k<<<kM, blk, 0, stream>>>(out, rms_attn, xn);
    gemm_k<false, false, false><<<dim3(3 * kD / 64, kM / 128), blk, 0, stream>>>(
        xn, w_qkv, nullptr, nullptr, nullptr, buf3, 3 * kD, kD);
    attn_k<<<dim3(kS / 64, kH, kB), blk, 0, stream>>>(buf3, eh);
    gemm_k<false, true, false><<<gD, blk, 0, stream>>>(
        eh, w_attn_out, nullptr, nullptr, out, out, kD, kD);

    // 6) FFN
    rmsnorm_k<<<kM, blk, 0, stream>>>(out, rms_ffn, xn);
    gemm_k<false, false, true><<<dim3(kFFN / 64, kM / 128), blk, 0, stream>>>(
        xn, w_ffn_gate, w_ffn_up, nullptr, nullptr, eh, kFFN, kD);
    gemm_k<false, true, false><<<gD, blk, 0, stream>>>(
        eh, w_ffn_out, nullptr, nullptr, out, out, kD, kFFN);
}

// Round 3
// 794.737 us; speedup vs baseline: 4.3095x; 4.3095x over previous
//
#include <hip/hip_runtime.h>
#include <hip/hip_bf16.h>
#include <math.h>

// Problem constants
constexpr int kB   = 2;
constexpr int kS   = 2048;
constexpr int kD   = 1024;
constexpr int kFFN = 4096;
constexpr int kM   = kB * kS;      // 4096 tokens
constexpr int kH   = 8;
constexpr int kDH  = 128;
constexpr int kNC  = 64;           // scan chunks
constexpr int kT   = kS / kNC;     // 32 steps per chunk

typedef unsigned short u16;
typedef __attribute__((ext_vector_type(8))) short short8;
typedef __attribute__((ext_vector_type(4))) float f32x4;

__device__ __forceinline__ float sigf(float x) { return 1.0f / (1.0f + __expf(-x)); }
__device__ __forceinline__ float bu2f(u16 u) { return __uint_as_float(((unsigned)u) << 16); }
__device__ __forceinline__ u16 f2bu(float f) {
    __hip_bfloat16 h = __float2bfloat16(f);
    return reinterpret_cast<u16&>(h);
}
__device__ __forceinline__ void async16(const void* g, void* l) {
    __builtin_amdgcn_global_load_lds((const __attribute__((address_space(1))) void*)g,
                                     (__attribute__((address_space(3))) void*)l, 16, 0, 0);
}

// ---------------- RMSNorm: f32 in, bf16 out ---------------------------------
__global__ __launch_bounds__(256) void rmsnorm_k(const float* __restrict__ x,
                                                 const float* __restrict__ w,
                                                 u16* __restrict__ o)
{
    __shared__ float red[4];
    const int row = blockIdx.x;
    const int t = threadIdx.x;
    float4 v = ((const float4*)(x + (size_t)row * kD))[t];
    float ss = v.x*v.x + v.y*v.y + v.z*v.z + v.w*v.w;
    #pragma unroll
    for (int m = 32; m; m >>= 1) ss += __shfl_xor(ss, m);
    if ((t & 63) == 0) red[t >> 6] = ss;
    __syncthreads();
    float tot = red[0] + red[1] + red[2] + red[3];
    float r = rsqrtf(tot * (1.0f / (float)kD) + 1e-6f);
    float4 wv = ((const float4*)w)[t];
    ushort4 u;
    u.x = f2bu(v.x * r * wv.x); u.y = f2bu(v.y * r * wv.y);
    u.z = f2bu(v.z * r * wv.z); u.w = f2bu(v.w * r * wv.w);
    ((ushort4*)(o + (size_t)row * kD))[t] = u;
}

// ---------------- Routing: pure f32 from x (top-k must not see bf16) --------
__global__ __launch_bounds__(64) void routing_k(const float* __restrict__ x,
                                                const float* __restrict__ wmix,
                                                const float* __restrict__ gw,
                                                float* __restrict__ wts,
                                                int* __restrict__ idx)
{
    const int row = blockIdx.x;
    const int lane = threadIdx.x;
    const float* xr = x + (size_t)row * kD;
    float ss = 0.0f;
    for (int d = lane; d < kD; d += 64) { float v = xr[d]; ss = fmaf(v, v, ss); }
    #pragma unroll
    for (int m = 32; m; m >>= 1) ss += __shfl_xor(ss, m);
    float r = rsqrtf(ss * (1.0f / (float)kD) + 1e-6f);

    float a0 = 0, a1 = 0, a2 = 0, a3 = 0;
    for (int d = lane; d < kD; d += 64) {
        float xv = xr[d] * wmix[d];          // r factored out (scalar>0: order-invariant for top-k)
        float4 g = ((const float4*)gw)[d];
        a0 = fmaf(xv, g.x, a0);
        a1 = fmaf(xv, g.y, a1);
        a2 = fmaf(xv, g.z, a2);
        a3 = fmaf(xv, g.w, a3);
    }
    #pragma unroll
    for (int m = 32; m; m >>= 1) {
        a0 += __shfl_xor(a0, m);
        a1 += __shfl_xor(a1, m);
        a2 += __shfl_xor(a2, m);
        a3 += __shfl_xor(a3, m);
    }
    if (lane == 0) {
        float a[4] = {a0, a1, a2, a3};
        int i0 = 0; float v0 = a[0];
        #pragma unroll
        for (int e = 1; e < 4; ++e) if (a[e] > v0) { v0 = a[e]; i0 = e; }
        int i1 = -1; float v1 = -INFINITY;
        #pragma unroll
        for (int e = 0; e < 4; ++e) if (e != i0 && a[e] > v1) { v1 = a[e]; i1 = e; }
        float e1 = __expf(r * (v1 - v0));
        float dn = 1.0f + e1;
        wts[row * 2 + 0] = 1.0f / dn;
        wts[row * 2 + 1] = e1 / dn;
        idx[row * 2 + 0] = i0;
        idx[row * 2 + 1] = i1;
    }
}

// ---------------- Transpose-convert: f32 [rows][cols] -> bf16 [cols][rows] --
__global__ __launch_bounds__(256) void transp_k(const float* __restrict__ src,
                                                u16* __restrict__ dst,
                                                int rows, int cols)
{
    __shared__ float t[32][33];
    const int c0 = blockIdx.x * 32, r0 = blockIdx.y * 32;
    const int tc = threadIdx.x & 31, tr4 = (threadIdx.x >> 5) * 4;
    #pragma unroll
    for (int i = 0; i < 4; ++i)
        t[tr4 + i][tc] = src[(size_t)(r0 + tr4 + i) * cols + c0 + tc];
    __syncthreads();
    #pragma unroll
    for (int i = 0; i < 4; ++i) {
        int cc = tr4 + i;
        dst[(size_t)(c0 + cc) * rows + r0 + tc] = f2bu(t[tc][cc]);
    }
}

// ---------------- Bias pack: [E][3072] = bg|bv|bd ---------------------------
__global__ __launch_bounds__(256) void biaspack_k(const float* __restrict__ bg,
                                                  const float* __restrict__ bv,
                                                  const float* __restrict__ bd,
                                                  float* __restrict__ pb)
{
    int e = blockIdx.y;
    int r = blockIdx.x * 256 + threadIdx.x;   // 0..3071
    const float* src = (r < 1024) ? bg : (r < 2048) ? bv : bd;
    pb[e * 3072 + r] = src[e * 1024 + (r & 1023)];
}

// ---------------- bf16 MFMA GEMM (m97 structure) -----------------------------
// C[M,N] = A[M,K] @ BT[N,K]^T.  BM=128, BN=32*WN, BK=32, 256 threads (4 waves 2x2).
template<int WN, bool BIAS, bool RES, bool SILU, bool MUL, bool OBF>
__global__ __launch_bounds__(256) void gemm_bf16_k(
    const u16* __restrict__ A, const u16* __restrict__ BT,
    const float* __restrict__ bias, const float* __restrict__ res,
    const u16* __restrict__ mulsrc, void* __restrict__ Cout,
    int N, int K)
{
    constexpr int BN = 32 * WN;
    __shared__ __align__(16) u16 As[128 * 32];
    __shared__ __align__(16) u16 Bs[BN * 32];
    const int tid = threadIdx.x;
    const int lane = tid & 63;
    const int w = tid >> 6;
    const int wr = w >> 1, wc = w & 1;
    const int bm = blockIdx.y * 128, bn = blockIdx.x * BN;
    const int fr = lane & 15, fk = (lane >> 4) * 8;

    const u16* gA1 = A + (size_t)(bm + (tid >> 2)) * K + (tid & 3) * 8;
    const u16* gA2 = gA1 + (size_t)64 * K;
    const u16* gB1 = BT + (size_t)(bn + (tid >> 2)) * K + (tid & 3) * 8;
    const u16* gB2 = gB1 + (size_t)64 * K;
    u16* lA1 = As + tid * 8;
    u16* lA2 = As + (256 + tid) * 8;
    u16* lB1 = Bs + tid * 8;
    u16* lB2 = Bs + (256 + tid) * 8;

    f32x4 acc[4][WN];
    #pragma unroll
    for (int m = 0; m < 4; ++m)
        #pragma unroll
        for (int n = 0; n < WN; ++n) acc[m][n] = (f32x4){0.f, 0.f, 0.f, 0.f};

    const u16* pa = As + (wr * 64 + fr) * 32 + fk;
    const u16* pb = Bs + (wc * WN * 16 + fr) * 32 + fk;

    for (int k0 = 0; k0 < K; k0 += 32) {
        async16(gA1 + k0, lA1);
        async16(gA2 + k0, lA2);
        async16(gB1 + k0, lB1);
        if constexpr (WN == 4) async16(gB2 + k0, lB2);
        __syncthreads();
        short8 a[4], b[WN];
        #pragma unroll
        for (int m = 0; m < 4; ++m) a[m] = *(const short8*)(pa + m * 512);
        #pragma unroll
        for (int n = 0; n < WN; ++n) b[n] = *(const short8*)(pb + n * 512);
        #pragma unroll
        for (int m = 0; m < 4; ++m)
            #pragma unroll
            for (int n = 0; n < WN; ++n)
                acc[m][n] = __builtin_amdgcn_mfma_f32_16x16x32_bf16(a[m], b[n], acc[m][n], 0, 0, 0);
        __syncthreads();
    }

    const int orow0 = bm + wr * 64 + ((lane >> 4) << 2);
    const int ocol0 = bn + wc * WN * 16 + fr;
    float bi[WN];
    if constexpr (BIAS) {
        #pragma unroll
        for (int n = 0; n < WN; ++n) bi[n] = bias[ocol0 + n * 16];
    }
    #pragma unroll
    for (int m = 0; m < 4; ++m) {
        #pragma unroll
        for (int r = 0; r < 4; ++r) {
            const int row = orow0 + m * 16 + r;
            const size_t ro = (size_t)row * N;
            #pragma unroll
            for (int n = 0; n < WN; ++n) {
                const size_t off = ro + ocol0 + n * 16;
                float v = acc[m][n][r];
                if constexpr (BIAS) v += bi[n];
                if constexpr (SILU) v = v * sigf(v);
                if constexpr (MUL)  v *= bu2f(mulsrc[off]);
                if constexpr (RES)  v += res[off];
                if constexpr (OBF)  ((u16*)Cout)[off] = f2bu(v);
                else                ((float*)Cout)[off] = v;
            }
        }
    }
}

// ---------------- minGRU chunked scan; gvd bf16 [M][3072] = g|v|d ------------
__global__ __launch_bounds__(256) void scan1_k(const u16* __restrict__ gvd,
                                               float* __restrict__ sumA,
                                               float* __restrict__ sumX)
{
    int i = blockIdx.x * 256 + threadIdx.x;      // [0, kB*kNC*kD)
    int d = i & (kD - 1);
    int c = (i >> 10) & (kNC - 1);
    int b = i >> 16;
    size_t base = ((size_t)b * kS + c * kT) * 3072 + d;
    float A = 1.0f, X = 0.0f;
    for (int t = 0; t < kT; ++t) {
        size_t ix = base + (size_t)t * 3072;
        float xs = sigf(bu2f(gvd[ix])) * tanhf(bu2f(gvd[ix + 1024]));
        float a  = 0.001f + 0.998f * sigf(bu2f(gvd[ix + 2048]));
        A *= a;
        X = fmaf(a, X, xs);
    }
    sumA[c * (kB * kD) + b * kD + d] = A;
    sumX[c * (kB * kD) + b * kD + d] = X;
}

__global__ __launch_bounds__(256) void scan2_k(const float* __restrict__ sumA,
                                               const float* __restrict__ sumX,
                                               float* __restrict__ carry)
{
    int bd = blockIdx.x * 256 + threadIdx.x;     // [0, kB*kD)
    float h = 0.0f;
    for (int c = 0; c < kNC; ++c) {
        carry[c * (kB * kD) + bd] = h;
        h = fmaf(sumA[c * (kB * kD) + bd], h, sumX[c * (kB * kD) + bd]);
    }
}

__global__ __launch_bounds__(256) void scan3_k(const u16* __restrict__ gvd,
                                               const float* __restrict__ carry,
                                               u16* __restrict__ hout)
{
    int i = blockIdx.x * 256 + threadIdx.x;
    int d = i & (kD - 1);
    int c = (i >> 10) & (kNC - 1);
    int b = i >> 16;
    size_t base = ((size_t)b * kS + c * kT) * 3072 + d;
    size_t obase = ((size_t)b * kS + c * kT) * kD + d;
    float h = carry[c * (kB * kD) + b * kD + d];
    for (int t = 0; t < kT; ++t) {
        size_t ix = base + (size_t)t * 3072;
        float xs = sigf(bu2f(gvd[ix])) * tanhf(bu2f(gvd[ix + 1024]));
        float a  = 0.001f + 0.998f * sigf(bu2f(gvd[ix + 2048]));
        h = fmaf(a, h, xs);
        hout[obase + (size_t)t * kD] = f2bu(h);
    }
}

// ---------------- MoE mix: out = x + w0*eh[i0] + w1*eh[i1] (eh bf16) --------
__global__ __launch_bounds__(256) void mix_k(const float* __restrict__ x,
                                             const u16* __restrict__ ehb,
                                             const float* __restrict__ wts,
                                             const int* __restrict__ idx,
                                             float* __restrict__ xo)
{
    size_t i = (size_t)blockIdx.x * 256 + threadIdx.x;  // 4-elem group index
    int m = (int)(i >> 8);
    float w0 = wts[m * 2 + 0], w1 = wts[m * 2 + 1];
    int e0 = idx[m * 2 + 0], e1 = idx[m * 2 + 1];
    size_t MD4 = (size_t)kM * (kD / 4);
    float4 xv = ((const float4*)x)[i];
    ushort4 h0 = ((const ushort4*)ehb)[(size_t)e0 * MD4 + i];
    ushort4 h1 = ((const ushort4*)ehb)[(size_t)e1 * MD4 + i];
    float4 o;
    o.x = xv.x + w0 * bu2f(h0.x) + w1 * bu2f(h1.x);
    o.y = xv.y + w0 * bu2f(h0.y) + w1 * bu2f(h1.y);
    o.z = xv.z + w0 * bu2f(h0.z) + w1 * bu2f(h1.z);
    o.w = xv.w + w0 * bu2f(h0.w) + w1 * bu2f(h1.w);
    ((float4*)xo)[i] = o;
}

// ---------------- Sliding-window attention (f32 in, bf16 out) ---------------
__global__ __launch_bounds__(256) void attn_k(const float* __restrict__ qkv,
                                              u16* __restrict__ aob)
{
    constexpr int TQ = 64;
    constexpr int QP = 129;
    constexpr int VP = 132;
    constexpr int SP = 194;
    __shared__ float Qs[TQ][QP];
    __shared__ float Ks[TQ][QP];
    __shared__ float Vs[TQ][VP];
    __shared__ float Ss[TQ][SP];
    __shared__ float Ls[TQ];

    const int tid = threadIdx.x;
    const int q0 = blockIdx.x * TQ;
    const int hh = blockIdx.y;
    const int bb = blockIdx.z;
    const size_t rs = 3 * kD;
    const float* base = qkv + (size_t)bb * kS * rs + hh * kDH;
    const float scale = 0.08838834764831845f;

    for (int f = tid; f < TQ * kDH / 4; f += 256) {
        int r = f >> 5, d4 = (f & 31) * 4;
        float4 v = *(const float4*)(base + (size_t)(q0 + r) * rs + d4);
        Qs[r][d4 + 0] = v.x; Qs[r][d4 + 1] = v.y;
        Qs[r][d4 + 2] = v.z; Qs[r][d4 + 3] = v.w;
    }

    const int kbase = q0 - 128;
    const int tx = tid & 15, ty = tid >> 4;

    for (int c = 0; c < 3; ++c) {
        int kb = kbase + c * 64;
        if (kb + 63 < 0) continue;
        for (int f = tid; f < 64 * kDH / 4; f += 256) {
            int r = f >> 5, d4 = (f & 31) * 4;
            int kg = kb + r; kg = kg < 0 ? 0 : kg;
            float4 v = *(const float4*)(base + (size_t)kg * rs + kD + d4);
            Ks[r][d4 + 0] = v.x; Ks[r][d4 + 1] = v.y;
            Ks[r][d4 + 2] = v.z; Ks[r][d4 + 3] = v.w;
        }
        __syncthreads();
        float sa[4][4] = {};
        #pragma unroll 4
        for (int d = 0; d < kDH; ++d) {
            float qv[4], kv[4];
            #pragma unroll
            for (int i = 0; i < 4; ++i) qv[i] = Qs[ty * 4 + i][d];
            #pragma unroll
            for (int j = 0; j < 4; ++j) kv[j] = Ks[tx * 4 + j][d];
            #pragma unroll
            for (int i = 0; i < 4; ++i)
                #pragma unroll
                for (int j = 0; j < 4; ++j)
                    sa[i][j] = fmaf(qv[i], kv[j], sa[i][j]);
        }
        #pragma unroll
        for (int i = 0; i < 4; ++i)
            #pragma unroll
            for (int j = 0; j < 4; ++j)
                Ss[ty * 4 + i][c * 64 + tx * 4 + j] = sa[i][j] * scale;
        __syncthreads();
    }

    {
        int q = tid >> 2, g = tid & 3;
        int klo = q + 1;
        int t2 = 128 - q0; if (t2 > klo) klo = t2;
        int khi = q + 128;
        float m = -INFINITY;
        for (int k = klo + g; k <= khi; k += 4) m = fmaxf(m, Ss[q][k]);
        m = fmaxf(m, __shfl_xor(m, 1));
        m = fmaxf(m, __shfl_xor(m, 2));
        float l = 0.0f;
        for (int k = g; k < 192; k += 4) {
            float p = 0.0f;
            if (k >= klo && k <= khi) p = __expf(Ss[q][k] - m);
            Ss[q][k] = p;
            l += p;
        }
        l += __shfl_xor(l, 1);
        l += __shfl_xor(l, 2);
        if (g == 0) Ls[q] = l;
    }
    __syncthreads();

    float oa[4][8] = {};
    for (int c = 0; c < 3; ++c) {
        int kb = kbase + c * 64;
        if (kb + 63 < 0) continue;
        for (int f = tid; f < 64 * kDH / 4; f += 256) {
            int r = f >> 5, d4 = (f & 31) * 4;
            int kg = kb + r; kg = kg < 0 ? 0 : kg;
            float4 v = *(const float4*)(base + (size_t)kg * rs + 2 * kD + d4);
            *(float4*)&Vs[r][d4] = v;
        }
        __syncthreads();
        for (int k = 0; k < 64; ++k) {
            float p[4];
            #pragma unroll
            for (int i = 0; i < 4; ++i) p[i] = Ss[ty * 4 + i][c * 64 + k];
            const float4 v0 = *(const float4*)&Vs[k][tx * 8];
            const float4 v1 = *(const float4*)&Vs[k][tx * 8 + 4];
            const float vv[8] = {v0.x, v0.y, v0.z, v0.w, v1.x, v1.y, v1.z, v1.w};
            #pragma unroll
            for (int i = 0; i < 4; ++i)
                #pragma unroll
                for (int u = 0; u < 8; ++u)
                    oa[i][u] = fmaf(p[i], vv[u], oa[i][u]);
        }
        __syncthreads();
    }

    #pragma unroll
    for (int i = 0; i < 4; ++i) {
        int q = ty * 4 + i;
        float inv = 1.0f / Ls[q];
        u16* orow = aob + ((size_t)bb * kS + q0 + q) * kD + hh * kDH + tx * 8;
        ushort4 u0, u1;
        u0.x = f2bu(oa[i][0] * inv); u0.y = f2bu(oa[i][1] * inv);
        u0.z = f2bu(oa[i][2] * inv); u0.w = f2bu(oa[i][3] * inv);
        u1.x = f2bu(oa[i][4] * inv); u1.y = f2bu(oa[i][5] * inv);
        u1.z = f2bu(oa[i][6] * inv); u1.w = f2bu(oa[i][7] * inv);
        *(ushort4*)orow = u0;
        *(ushort4*)(orow + 4) = u1;
    }
}

// ---------------------------------------------------------------------------
extern "C" void kernel_launch(void* const* d_in, const int* in_sizes, int n_in,
                              void* d_out, int out_size, void* d_ws, size_t ws_size,
                              hipStream_t stream)
{
    (void)in_sizes; (void)n_in; (void)out_size; (void)ws_size;

    const float* x          = (const float*)d_in[0];
    const float* rms_mix    = (const float*)d_in[1];
    const float* gate_w     = (const float*)d_in[2];
    const float* Wg         = (const float*)d_in[3];
    const float* bg         = (const float*)d_in[4];
    const float* Wv         = (const float*)d_in[5];
    const float* bv         = (const float*)d_in[6];
    const float* Wd         = (const float*)d_in[7];
    const float* bd         = (const float*)d_in[8];
    const float* rms_attn   = (const float*)d_in[9];
    const float* w_qkv      = (const float*)d_in[10];
    const float* w_attn_out = (const float*)d_in[11];
    const float* rms_ffn    = (const float*)d_in[12];
    const float* w_ffn_gate = (const float*)d_in[13];
    const float* w_ffn_up   = (const float*)d_in[14];
    const float* w_ffn_out  = (const float*)d_in[15];
    float* out = (float*)d_out;

    const size_t MD = (size_t)kM * kD;
    char* p = (char*)d_ws;
    auto take = [&](size_t n) { char* r = p; p += (n + 255) & ~(size_t)255; return r; };

    // ~122 MB total (< R1's proven 130 MB footprint)
    u16*   xnb   = (u16*)take(MD * 2);                 // 8 MB  bf16 xn
    float* qbuf  = (float*)take(MD * 3 * 4);           // 48 MB f32 qkv | gvd bf16 | hidB bf16
    u16*   gvd   = (u16*)qbuf;
    u16*   hidB  = (u16*)qbuf;
    u16*   ehb   = (u16*)take(4 * MD * 2);             // 32 MB expert h bf16 | hidA bf16
    u16*   hidA  = ehb;
    u16*   aob   = (u16*)take(MD * 2);                 // 8 MB
    u16*   wbuf  = (u16*)take(12ull * 1024 * 1024 * 2);// 24 MB transposed-weight arena
    float* pbias = (float*)take(4 * 3072 * 4);
    float* sumA  = (float*)take((size_t)kNC * kB * kD * 4);
    float* sumX  = (float*)take((size_t)kNC * kB * kD * 4);
    float* carry = (float*)take((size_t)kNC * kB * kD * 4);
    float* wts   = (float*)take((size_t)2 * kM * 4);
    int*   tidx  = (int*)take((size_t)2 * kM * 4);

    const dim3 blk(256);
    const size_t M1 = 1024ull * 1024;   // u16 elements per 1024x1024 matrix

    // ---- stage 1: rmsnorm + routing (routing from f32 x: top-k safe) ----
    rmsnorm_k<<<kM, blk, 0, stream>>>(x, rms_mix, xnb);
    routing_k<<<kM, dim3(64), 0, stream>>>(x, rms_mix, gate_w, wts, tidx);
    biaspack_k<<<dim3(12, 4), blk, 0, stream>>>(bg, bv, bd, pbias);

    // ---- experts: transpose weights per expert into arena, GEMM, scan ----
    const int scan_blocks = kB * kD * kNC / 256;
    for (int e = 0; e < 4; ++e) {
        const size_t wo = (size_t)e * kD * kD;
        transp_k<<<dim3(32, 32), blk, 0, stream>>>(Wg + wo, wbuf, 1024, 1024);
        transp_k<<<dim3(32, 32), blk, 0, stream>>>(Wv + wo, wbuf + M1, 1024, 1024);
        transp_k<<<dim3(32, 32), blk, 0, stream>>>(Wd + wo, wbuf + 2 * M1, 1024, 1024);
        gemm_bf16_k<4, true, false, false, false, true><<<dim3(3072 / 128, kM / 128), blk, 0, stream>>>(
            xnb, wbuf, pbias + e * 3072, nullptr, nullptr, gvd, 3072, 1024);
        scan1_k<<<scan_blocks, blk, 0, stream>>>(gvd, sumA, sumX);
        scan2_k<<<kB * kD / 256, blk, 0, stream>>>(sumA, sumX, carry);
        scan3_k<<<scan_blocks, blk, 0, stream>>>(gvd, carry, ehb + (size_t)e * MD);
    }

    // ---- MoE mix -> out (x1) ----
    mix_k<<<(int)(MD / 1024), blk, 0, stream>>>(x, ehb, wts, tidx, out);

    // ---- attention ----
    rmsnorm_k<<<kM, blk, 0, stream>>>(out, rms_attn, xnb);
    transp_k<<<dim3(96, 32), blk, 0, stream>>>(w_qkv, wbuf, 1024, 3072);
    gemm_bf16_k<4, false, false, false, false, false><<<dim3(3072 / 128, kM / 128), blk, 0, stream>>>(
        xnb, wbuf, nullptr, nullptr, nullptr, qbuf, 3072, 1024);
    attn_k<<<dim3(kS / 64, kH, kB), blk, 0, stream>>>(qbuf, aob);
    transp_k<<<dim3(32, 32), blk, 0, stream>>>(w_attn_out, wbuf + 3 * M1, 1024, 1024);
    gemm_bf16_k<2, false, true, false, false, false><<<dim3(1024 / 64, kM / 128), blk, 0, stream>>>(
        aob, wbuf + 3 * M1, nullptr, out, nullptr, out, 1024, 1024);

    // ---- FFN ----
    rmsnorm_k<<<kM, blk, 0, stream>>>(out, rms_ffn, xnb);
    transp_k<<<dim3(128, 32), blk, 0, stream>>>(w_ffn_gate, wbuf, 1024, 4096);
    transp_k<<<dim3(128, 32), blk, 0, stream>>>(w_ffn_up, wbuf + 4 * M1, 1024, 4096);
    transp_k<<<dim3(32, 128), blk, 0, stream>>>(w_ffn_out, wbuf + 8 * M1, 4096, 1024);
    gemm_bf16_k<4, false, false, true, false, true><<<dim3(4096 / 128, kM / 128), blk, 0, stream>>>(
        xnb, wbuf, nullptr, nullptr, nullptr, hidA, 4096, 1024);
    gemm_bf16_k<4, false, false, false, true, true><<<dim3(4096 / 128, kM / 128), blk, 0, stream>>>(
        xnb, wbuf + 4 * M1, nullptr, nullptr, hidA, hidB, 4096, 1024);
    gemm_bf16_k<2, false, true, false, false, false><<<dim3(1024 / 64, kM / 128), blk, 0, stream>>>(
        hidB, wbuf + 8 * M1, nullptr, out, nullptr, out, 1024, 4096);
}

// Round 4
// 726.232 us; speedup vs baseline: 4.7160x; 1.0943x over previous
//
#include <hip/hip_runtime.h>
#include <hip/hip_bf16.h>
#include <math.h>

// Problem constants
constexpr int kB   = 2;
constexpr int kS   = 2048;
constexpr int kD   = 1024;
constexpr int kFFN = 4096;
constexpr int kM   = kB * kS;      // 4096 tokens
constexpr int kH   = 8;
constexpr int kDH  = 128;
constexpr int kNC  = 64;           // scan chunks
constexpr int kT   = kS / kNC;     // 32 steps per chunk

typedef unsigned short u16;
typedef __attribute__((ext_vector_type(8))) short short8;
typedef __attribute__((ext_vector_type(4))) float f32x4;

__device__ __forceinline__ float sigf(float x) { return 1.0f / (1.0f + __expf(-x)); }
__device__ __forceinline__ float bu2f(u16 u) { return __uint_as_float(((unsigned)u) << 16); }
__device__ __forceinline__ u16 f2bu(float f) {
    __hip_bfloat16 h = __float2bfloat16(f);
    return reinterpret_cast<u16&>(h);
}
__device__ __forceinline__ void async16(const void* g, void* l) {
    __builtin_amdgcn_global_load_lds((const __attribute__((address_space(1))) void*)g,
                                     (__attribute__((address_space(3))) void*)l, 16, 0, 0);
}

// ---------------- RMSNorm: f32 in, bf16 out ---------------------------------
__global__ __launch_bounds__(256) void rmsnorm_k(const float* __restrict__ x,
                                                 const float* __restrict__ w,
                                                 u16* __restrict__ o)
{
    __shared__ float red[4];
    const int row = blockIdx.x;
    const int t = threadIdx.x;
    float4 v = ((const float4*)(x + (size_t)row * kD))[t];
    float ss = v.x*v.x + v.y*v.y + v.z*v.z + v.w*v.w;
    #pragma unroll
    for (int m = 32; m; m >>= 1) ss += __shfl_xor(ss, m);
    if ((t & 63) == 0) red[t >> 6] = ss;
    __syncthreads();
    float tot = red[0] + red[1] + red[2] + red[3];
    float r = rsqrtf(tot * (1.0f / (float)kD) + 1e-6f);
    float4 wv = ((const float4*)w)[t];
    ushort4 u;
    u.x = f2bu(v.x * r * wv.x); u.y = f2bu(v.y * r * wv.y);
    u.z = f2bu(v.z * r * wv.z); u.w = f2bu(v.w * r * wv.w);
    ((ushort4*)(o + (size_t)row * kD))[t] = u;
}

// ---------------- Routing: pure f32 from x (top-k must not see bf16) --------
__global__ __launch_bounds__(64) void routing_k(const float* __restrict__ x,
                                                const float* __restrict__ wmix,
                                                const float* __restrict__ gw,
                                                float* __restrict__ wts,
                                                int* __restrict__ idx)
{
    const int row = blockIdx.x;
    const int lane = threadIdx.x;
    const float* xr = x + (size_t)row * kD;
    float ss = 0.0f;
    for (int d = lane; d < kD; d += 64) { float v = xr[d]; ss = fmaf(v, v, ss); }
    #pragma unroll
    for (int m = 32; m; m >>= 1) ss += __shfl_xor(ss, m);
    float r = rsqrtf(ss * (1.0f / (float)kD) + 1e-6f);

    float a0 = 0, a1 = 0, a2 = 0, a3 = 0;
    for (int d = lane; d < kD; d += 64) {
        float xv = xr[d] * wmix[d];
        float4 g = ((const float4*)gw)[d];
        a0 = fmaf(xv, g.x, a0);
        a1 = fmaf(xv, g.y, a1);
        a2 = fmaf(xv, g.z, a2);
        a3 = fmaf(xv, g.w, a3);
    }
    #pragma unroll
    for (int m = 32; m; m >>= 1) {
        a0 += __shfl_xor(a0, m);
        a1 += __shfl_xor(a1, m);
        a2 += __shfl_xor(a2, m);
        a3 += __shfl_xor(a3, m);
    }
    if (lane == 0) {
        float a[4] = {a0, a1, a2, a3};
        int i0 = 0; float v0 = a[0];
        #pragma unroll
        for (int e = 1; e < 4; ++e) if (a[e] > v0) { v0 = a[e]; i0 = e; }
        int i1 = -1; float v1 = -INFINITY;
        #pragma unroll
        for (int e = 0; e < 4; ++e) if (e != i0 && a[e] > v1) { v1 = a[e]; i1 = e; }
        float e1 = __expf(r * (v1 - v0));
        float dn = 1.0f + e1;
        wts[row * 2 + 0] = 1.0f / dn;
        wts[row * 2 + 1] = e1 / dn;
        idx[row * 2 + 0] = i0;
        idx[row * 2 + 1] = i1;
    }
}

// ---------------- Transpose-convert: f32 [rows][cols] -> bf16 [cols][rows] --
__global__ __launch_bounds__(256) void transp_k(const float* __restrict__ src,
                                                u16* __restrict__ dst,
                                                int rows, int cols,
                                                size_t sstride, size_t dstride)
{
    __shared__ float t[32][33];
    const float* s = src + blockIdx.z * sstride;
    u16* d = dst + blockIdx.z * dstride;
    const int c0 = blockIdx.x * 32, r0 = blockIdx.y * 32;
    const int tc = threadIdx.x & 31, tr4 = (threadIdx.x >> 5) * 4;
    #pragma unroll
    for (int i = 0; i < 4; ++i)
        t[tr4 + i][tc] = s[(size_t)(r0 + tr4 + i) * cols + c0 + tc];
    __syncthreads();
    #pragma unroll
    for (int i = 0; i < 4; ++i) {
        int cc = tr4 + i;
        d[(size_t)(c0 + cc) * rows + r0 + tc] = f2bu(t[tc][cc]);
    }
}

// ---------------- Bias pack: [E][3072] = bg|bv|bd ---------------------------
__global__ __launch_bounds__(256) void biaspack_k(const float* __restrict__ bg,
                                                  const float* __restrict__ bv,
                                                  const float* __restrict__ bd,
                                                  float* __restrict__ pb)
{
    int e = blockIdx.y;
    int r = blockIdx.x * 256 + threadIdx.x;   // 0..3071
    const float* src = (r < 1024) ? bg : (r < 2048) ? bv : bd;
    pb[e * 3072 + r] = src[e * 1024 + (r & 1023)];
}

// ---------------- bf16 MFMA GEMM (m97 structure) -----------------------------
// C[M,N] = A[M,K] @ BT[N,K]^T.  BM=128, BN=32*WN, BK=32, 256 threads (4 waves 2x2).
// DUAL: second B matrix BT2, epilogue silu(acc)*acc2.
template<int WN, bool BIAS, bool RES, bool DUAL, bool OBF>
__global__ __launch_bounds__(256) void gemm_bf16_k(
    const u16* __restrict__ A, const u16* __restrict__ BT,
    const u16* __restrict__ BT2,
    const float* __restrict__ bias, const float* __restrict__ res,
    void* __restrict__ Cout, int N, int K)
{
    constexpr int BN = 32 * WN;
    __shared__ __align__(16) u16 As[128 * 32];
    __shared__ __align__(16) u16 Bs[BN * 32];
    __shared__ __align__(16) u16 Bs2[DUAL ? BN * 32 : 16];
    const int tid = threadIdx.x;
    const int lane = tid & 63;
    const int w = tid >> 6;
    const int wr = w >> 1, wc = w & 1;
    const int bm = blockIdx.y * 128, bn = blockIdx.x * BN;
    const int fr = lane & 15, fk = (lane >> 4) * 8;

    const u16* gA1 = A + (size_t)(bm + (tid >> 2)) * K + (tid & 3) * 8;
    const u16* gA2 = gA1 + (size_t)64 * K;
    const u16* gB1 = BT + (size_t)(bn + (tid >> 2)) * K + (tid & 3) * 8;
    const u16* gB2 = gB1 + (size_t)64 * K;
    u16* lA1 = As + tid * 8;
    u16* lA2 = As + (256 + tid) * 8;
    u16* lB1 = Bs + tid * 8;
    u16* lB2 = Bs + (256 + tid) * 8;

    f32x4 acc[4][WN];
    f32x4 acc2[DUAL ? 4 : 1][DUAL ? WN : 1];
    #pragma unroll
    for (int m = 0; m < 4; ++m)
        #pragma unroll
        for (int n = 0; n < WN; ++n) acc[m][n] = (f32x4){0.f, 0.f, 0.f, 0.f};
    if constexpr (DUAL) {
        #pragma unroll
        for (int m = 0; m < 4; ++m)
            #pragma unroll
            for (int n = 0; n < WN; ++n) acc2[m][n] = (f32x4){0.f, 0.f, 0.f, 0.f};
    }

    const u16* pa = As + (wr * 64 + fr) * 32 + fk;
    const u16* pb = Bs + (wc * WN * 16 + fr) * 32 + fk;
    const u16* pb2 = Bs2 + (wc * WN * 16 + fr) * 32 + fk;

    for (int k0 = 0; k0 < K; k0 += 32) {
        async16(gA1 + k0, lA1);
        async16(gA2 + k0, lA2);
        async16(gB1 + k0, lB1);
        if constexpr (WN == 4) async16(gB2 + k0, lB2);
        if constexpr (DUAL) {
            const u16* gC1 = BT2 + (size_t)(bn + (tid >> 2)) * K + (tid & 3) * 8;
            async16(gC1 + k0, Bs2 + tid * 8);
            async16(gC1 + (size_t)64 * K + k0, Bs2 + (256 + tid) * 8);
        }
        __syncthreads();
        short8 a[4], b[WN];
        #pragma unroll
        for (int m = 0; m < 4; ++m) a[m] = *(const short8*)(pa + m * 512);
        #pragma unroll
        for (int n = 0; n < WN; ++n) b[n] = *(const short8*)(pb + n * 512);
        #pragma unroll
        for (int m = 0; m < 4; ++m)
            #pragma unroll
            for (int n = 0; n < WN; ++n)
                acc[m][n] = __builtin_amdgcn_mfma_f32_16x16x32_bf16(a[m], b[n], acc[m][n], 0, 0, 0);
        if constexpr (DUAL) {
            short8 b2[WN];
            #pragma unroll
            for (int n = 0; n < WN; ++n) b2[n] = *(const short8*)(pb2 + n * 512);
            #pragma unroll
            for (int m = 0; m < 4; ++m)
                #pragma unroll
                for (int n = 0; n < WN; ++n)
                    acc2[m][n] = __builtin_amdgcn_mfma_f32_16x16x32_bf16(a[m], b2[n], acc2[m][n], 0, 0, 0);
        }
        __syncthreads();
    }

    const int orow0 = bm + wr * 64 + ((lane >> 4) << 2);
    const int ocol0 = bn + wc * WN * 16 + fr;
    float bi[WN];
    if constexpr (BIAS) {
        #pragma unroll
        for (int n = 0; n < WN; ++n) bi[n] = bias[ocol0 + n * 16];
    }
    #pragma unroll
    for (int m = 0; m < 4; ++m) {
        #pragma unroll
        for (int r = 0; r < 4; ++r) {
            const int row = orow0 + m * 16 + r;
            const size_t ro = (size_t)row * N;
            #pragma unroll
            for (int n = 0; n < WN; ++n) {
                const size_t off = ro + ocol0 + n * 16;
                float v = acc[m][n][r];
                if constexpr (BIAS) v += bi[n];
                if constexpr (DUAL) v = v * sigf(v) * acc2[m][n][r];
                if constexpr (RES)  v += res[off];
                if constexpr (OBF)  ((u16*)Cout)[off] = f2bu(v);
                else                ((float*)Cout)[off] = v;
            }
        }
    }
}

// ---------------- minGRU chunked scan; gvd bf16 [M][3072] = g|v|d ------------
__global__ __launch_bounds__(256) void scan1_k(const u16* __restrict__ gvd,
                                               float* __restrict__ sumA,
                                               float* __restrict__ sumX)
{
    int i = blockIdx.x * 256 + threadIdx.x;      // [0, kB*kNC*kD)
    int d = i & (kD - 1);
    int c = (i >> 10) & (kNC - 1);
    int b = i >> 16;
    size_t base = ((size_t)b * kS + c * kT) * 3072 + d;
    float A = 1.0f, X = 0.0f;
    for (int t = 0; t < kT; ++t) {
        size_t ix = base + (size_t)t * 3072;
        float xs = sigf(bu2f(gvd[ix])) * tanhf(bu2f(gvd[ix + 1024]));
        float a  = 0.001f + 0.998f * sigf(bu2f(gvd[ix + 2048]));
        A *= a;
        X = fmaf(a, X, xs);
    }
    sumA[c * (kB * kD) + b * kD + d] = A;
    sumX[c * (kB * kD) + b * kD + d] = X;
}

__global__ __launch_bounds__(256) void scan2_k(const float* __restrict__ sumA,
                                               const float* __restrict__ sumX,
                                               float* __restrict__ carry)
{
    int bd = blockIdx.x * 256 + threadIdx.x;     // [0, kB*kD)
    float h = 0.0f;
    for (int c = 0; c < kNC; ++c) {
        carry[c * (kB * kD) + bd] = h;
        h = fmaf(sumA[c * (kB * kD) + bd], h, sumX[c * (kB * kD) + bd]);
    }
}

__global__ __launch_bounds__(256) void scan3_k(const u16* __restrict__ gvd,
                                               const float* __restrict__ carry,
                                               u16* __restrict__ hout)
{
    int i = blockIdx.x * 256 + threadIdx.x;
    int d = i & (kD - 1);
    int c = (i >> 10) & (kNC - 1);
    int b = i >> 16;
    size_t base = ((size_t)b * kS + c * kT) * 3072 + d;
    size_t obase = ((size_t)b * kS + c * kT) * kD + d;
    float h = carry[c * (kB * kD) + b * kD + d];
    for (int t = 0; t < kT; ++t) {
        size_t ix = base + (size_t)t * 3072;
        float xs = sigf(bu2f(gvd[ix])) * tanhf(bu2f(gvd[ix + 1024]));
        float a  = 0.001f + 0.998f * sigf(bu2f(gvd[ix + 2048]));
        h = fmaf(a, h, xs);
        hout[obase + (size_t)t * kD] = f2bu(h);
    }
}

// ---------------- MoE mix: out = x + w0*eh[i0] + w1*eh[i1] (eh bf16) --------
__global__ __launch_bounds__(256) void mix_k(const float* __restrict__ x,
                                             const u16* __restrict__ ehb,
                                             const float* __restrict__ wts,
                                             const int* __restrict__ idx,
                                             float* __restrict__ xo)
{
    size_t i = (size_t)blockIdx.x * 256 + threadIdx.x;  // 4-elem group index
    int m = (int)(i >> 8);
    float w0 = wts[m * 2 + 0], w1 = wts[m * 2 + 1];
    int e0 = idx[m * 2 + 0], e1 = idx[m * 2 + 1];
    size_t MD4 = (size_t)kM * (kD / 4);
    float4 xv = ((const float4*)x)[i];
    ushort4 h0 = ((const ushort4*)ehb)[(size_t)e0 * MD4 + i];
    ushort4 h1 = ((const ushort4*)ehb)[(size_t)e1 * MD4 + i];
    float4 o;
    o.x = xv.x + w0 * bu2f(h0.x) + w1 * bu2f(h1.x);
    o.y = xv.y + w0 * bu2f(h0.y) + w1 * bu2f(h1.y);
    o.z = xv.z + w0 * bu2f(h0.z) + w1 * bu2f(h1.z);
    o.w = xv.w + w0 * bu2f(h0.w) + w1 * bu2f(h1.w);
    ((float4*)xo)[i] = o;
}

// ---------------- V transpose: qkvb V-part -> vT [b*H+h][128 d][2048 s] -----
__global__ __launch_bounds__(256) void transpV_k(const u16* __restrict__ qkvb,
                                                 u16* __restrict__ vT)
{
    __shared__ u16 t[64][68];
    const int tid = threadIdx.x;
    const int s0 = blockIdx.x * 64;
    const int d0 = blockIdx.y * 64;
    const int bh = blockIdx.z;
    const int bb = bh >> 3, hh = bh & 7;
    const u16* src = qkvb + (size_t)(bb * kS + s0) * 3072 + 2048 + hh * kDH + d0;
    for (int idx = tid; idx < 64 * 16; idx += 256) {
        int sl = idx >> 4, c4 = (idx & 15) * 4;
        *(ushort4*)&t[sl][c4] = *(const ushort4*)(src + (size_t)sl * 3072 + c4);
    }
    __syncthreads();
    u16* dst = vT + ((size_t)bh * kDH + d0) * kS + s0;
    for (int idx = tid; idx < 64 * 16; idx += 256) {
        int dl = idx >> 4, s4 = (idx & 15) * 4;
        ushort4 v;
        v.x = t[s4 + 0][dl]; v.y = t[s4 + 1][dl];
        v.z = t[s4 + 2][dl]; v.w = t[s4 + 3][dl];
        *(ushort4*)(dst + (size_t)dl * kS + s4) = v;
    }
}

// ---------------- MFMA sliding-window attention ------------------------------
// Block: (64-query tile, head, batch). 4 waves, 16 q each. Keys: 192 window.
__global__ __launch_bounds__(256) void attn_mfma_k(const u16* __restrict__ qkvb,
                                                   const u16* __restrict__ vT,
                                                   u16* __restrict__ aob)
{
    __shared__ __align__(16) u16 KV[26112];      // K: [192][136] | VT: [128][200]
    __shared__ __align__(16) u16 P[4 * 16 * 200];

    const int tid = threadIdx.x;
    const int lane = tid & 63;
    const int w = tid >> 6;
    const int fr = lane & 15, g = lane >> 4;
    const int q0 = blockIdx.x * 64;
    const int hh = blockIdx.y;
    const int bb = blockIdx.z;
    const int kbase = q0 - 128;
    const float scale = 0.08838834764831845f;    // 1/sqrt(128)

    const u16* qkv_b = qkvb + (size_t)bb * kS * 3072 + hh * kDH;

    // stage K [192][136]
    for (int idx = tid; idx < 192 * 16; idx += 256) {
        int k = idx >> 4, c = idx & 15;
        int kg = kbase + k; if (kg < 0) kg = 0;
        short8 v = *(const short8*)(qkv_b + (size_t)kg * 3072 + 1024 + c * 8);
        *(short8*)(&KV[k * 136 + c * 8]) = v;
    }
    // Q frags direct from global
    short8 qf[4];
    {
        const u16* qrow = qkv_b + (size_t)(q0 + w * 16 + fr) * 3072 + g * 8;
        #pragma unroll
        for (int s = 0; s < 4; ++s) qf[s] = *(const short8*)(qrow + s * 32);
    }
    __syncthreads();

    // QK^T: S[q][k], q = w*16+g*4+r, k = f*16+fr (in C/D layout)
    f32x4 sacc[12];
    #pragma unroll
    for (int f = 0; f < 12; ++f) sacc[f] = (f32x4){0.f, 0.f, 0.f, 0.f};
    #pragma unroll
    for (int s = 0; s < 4; ++s) {
        #pragma unroll
        for (int f = 0; f < 12; ++f) {
            short8 bfr = *(const short8*)(&KV[(f * 16 + fr) * 136 + s * 32 + g * 8]);
            sacc[f] = __builtin_amdgcn_mfma_f32_16x16x32_bf16(qf[s], bfr, sacc[f], 0, 0, 0);
        }
    }

    // mask + softmax (all in regs; rows are lane-local per r)
    float p[12][4];
    #pragma unroll
    for (int r = 0; r < 4; ++r) {
        const int ql = w * 16 + g * 4 + r;
        int kmin = 128 - q0; if (kmin < ql + 1) kmin = ql + 1;
        const int kmax = ql + 128;
        float mx = -1e30f;
        #pragma unroll
        for (int f = 0; f < 12; ++f) {
            int kl = f * 16 + fr;
            float sv = (kl >= kmin && kl <= kmax) ? sacc[f][r] * scale : -1e30f;
            p[f][r] = sv;
            mx = fmaxf(mx, sv);
        }
        mx = fmaxf(mx, __shfl_xor(mx, 1));
        mx = fmaxf(mx, __shfl_xor(mx, 2));
        mx = fmaxf(mx, __shfl_xor(mx, 4));
        mx = fmaxf(mx, __shfl_xor(mx, 8));
        float l = 0.f;
        #pragma unroll
        for (int f = 0; f < 12; ++f) { float e = __expf(p[f][r] - mx); p[f][r] = e; l += e; }
        l += __shfl_xor(l, 1);
        l += __shfl_xor(l, 2);
        l += __shfl_xor(l, 4);
        l += __shfl_xor(l, 8);
        float linv = 1.0f / l;
        #pragma unroll
        for (int f = 0; f < 12; ++f) p[f][r] *= linv;
    }

    // write P (bf16, already normalized) to LDS [wave][16 q][200 pitch]
    {
        u16* pw = &P[(w * 16) * 200];
        #pragma unroll
        for (int r = 0; r < 4; ++r)
            #pragma unroll
            for (int f = 0; f < 12; ++f)
                pw[(g * 4 + r) * 200 + f * 16 + fr] = f2bu(p[f][r]);
    }
    __syncthreads();   // all K reads + P writes done

    // stage VT [128][200] over KV
    {
        const u16* vrow = vT + (size_t)(bb * kH + hh) * kDH * kS;
        for (int idx = tid; idx < 128 * 25; idx += 256) {
            int d = idx / 25, c = idx % 25;
            if (c < 24) {
                int s0k = kbase + c * 8;
                short8 v;
                if (s0k < 0) v = (short8){0, 0, 0, 0, 0, 0, 0, 0};
                else v = *(const short8*)(vrow + (size_t)d * kS + s0k);
                *(short8*)(&KV[d * 200 + c * 8]) = v;
            }
        }
    }
    __syncthreads();

    // PV: O[q][d] = sum_k P[q][k] * VT[d][k]
    f32x4 oacc[8];
    #pragma unroll
    for (int f = 0; f < 8; ++f) oacc[f] = (f32x4){0.f, 0.f, 0.f, 0.f};
    const u16* pr = &P[(w * 16 + fr) * 200 + g * 8];
    #pragma unroll
    for (int s = 0; s < 6; ++s) {
        short8 afr = *(const short8*)(pr + s * 32);
        #pragma unroll
        for (int f = 0; f < 8; ++f) {
            short8 bfr = *(const short8*)(&KV[(f * 16 + fr) * 200 + s * 32 + g * 8]);
            oacc[f] = __builtin_amdgcn_mfma_f32_16x16x32_bf16(afr, bfr, oacc[f], 0, 0, 0);
        }
    }
    u16* orow = aob + ((size_t)(bb * kS + q0 + w * 16 + g * 4) * kD) + hh * kDH + fr;
    #pragma unroll
    for (int r = 0; r < 4; ++r)
        #pragma unroll
        for (int f = 0; f < 8; ++f)
            orow[(size_t)r * kD + f * 16] = f2bu(oacc[f][r]);
}

// ---------------------------------------------------------------------------
extern "C" void kernel_launch(void* const* d_in, const int* in_sizes, int n_in,
                              void* d_out, int out_size, void* d_ws, size_t ws_size,
                              hipStream_t stream)
{
    (void)in_sizes; (void)n_in; (void)out_size; (void)ws_size;

    const float* x          = (const float*)d_in[0];
    const float* rms_mix    = (const float*)d_in[1];
    const float* gate_w     = (const float*)d_in[2];
    const float* Wg         = (const float*)d_in[3];
    const float* bg         = (const float*)d_in[4];
    const float* Wv         = (const float*)d_in[5];
    const float* bv         = (const float*)d_in[6];
    const float* Wd         = (const float*)d_in[7];
    const float* bd         = (const float*)d_in[8];
    const float* rms_attn   = (const float*)d_in[9];
    const float* w_qkv      = (const float*)d_in[10];
    const float* w_attn_out = (const float*)d_in[11];
    const float* rms_ffn    = (const float*)d_in[12];
    const float* w_ffn_gate = (const float*)d_in[13];
    const float* w_ffn_up   = (const float*)d_in[14];
    const float* w_ffn_out  = (const float*)d_in[15];
    float* out = (float*)d_out;

    const size_t MD = (size_t)kM * kD;
    const size_t M1 = 1024ull * 1024;   // u16 elements per 1024x1024 matrix
    char* p = (char*)d_ws;
    auto take = [&](size_t n) { char* r = p; p += (n + 255) & ~(size_t)255; return r; };

    u16*   xnb   = (u16*)take(MD * 2);                  // 8.4 MB
    u16*   arena = (u16*)take((size_t)kM * kFFN * 2);   // 33.6 MB: gvd | qkvb | hidB
    u16*   gvd   = arena;
    u16*   qkvb  = arena;
    u16*   hidB  = arena;
    u16*   ehb   = (u16*)take(4 * MD * 2);              // 33.6 MB: eh x4 | aob+vT
    u16*   aob   = ehb;
    u16*   vTb   = ehb + MD;
    u16*   wbuf  = (u16*)take(12ull * M1 * 2);          // 25.2 MB transposed weights
    float* pbias = (float*)take(4 * 3072 * 4);
    float* sumA  = (float*)take((size_t)kNC * kB * kD * 4);
    float* sumX  = (float*)take((size_t)kNC * kB * kD * 4);
    float* carry = (float*)take((size_t)kNC * kB * kD * 4);
    float* wts   = (float*)take((size_t)2 * kM * 4);
    int*   tidx  = (int*)take((size_t)2 * kM * 4);

    const dim3 blk(256);

    // ---- expert weight transposes (z-batched) + bias pack ----
    transp_k<<<dim3(32, 32, 4), blk, 0, stream>>>(Wg, wbuf, 1024, 1024,
                                                  (size_t)kD * kD, 3 * M1);
    transp_k<<<dim3(32, 32, 4), blk, 0, stream>>>(Wv, wbuf + M1, 1024, 1024,
                                                  (size_t)kD * kD, 3 * M1);
    transp_k<<<dim3(32, 32, 4), blk, 0, stream>>>(Wd, wbuf + 2 * M1, 1024, 1024,
                                                  (size_t)kD * kD, 3 * M1);
    biaspack_k<<<dim3(12, 4), blk, 0, stream>>>(bg, bv, bd, pbias);

    // ---- stage 1: rmsnorm + routing ----
    rmsnorm_k<<<kM, blk, 0, stream>>>(x, rms_mix, xnb);
    routing_k<<<kM, dim3(64), 0, stream>>>(x, rms_mix, gate_w, wts, tidx);

    // ---- experts ----
    const int scan_blocks = kB * kD * kNC / 256;
    for (int e = 0; e < 4; ++e) {
        gemm_bf16_k<4, true, false, false, true><<<dim3(3072 / 128, kM / 128), blk, 0, stream>>>(
            xnb, wbuf + (size_t)e * 3 * M1, nullptr, pbias + e * 3072, nullptr, gvd, 3072, 1024);
        scan1_k<<<scan_blocks, blk, 0, stream>>>(gvd, sumA, sumX);
        scan2_k<<<kB * kD / 256, blk, 0, stream>>>(sumA, sumX, carry);
        scan3_k<<<scan_blocks, blk, 0, stream>>>(gvd, carry, ehb + (size_t)e * MD);
    }

    // ---- MoE mix -> out (x1) ----
    mix_k<<<(int)(MD / 1024), blk, 0, stream>>>(x, ehb, wts, tidx, out);

    // ---- attention ----
    rmsnorm_k<<<kM, blk, 0, stream>>>(out, rms_attn, xnb);
    transp_k<<<dim3(96, 32, 1), blk, 0, stream>>>(w_qkv, wbuf, 1024, 3072, 0, 0);
    gemm_bf16_k<4, false, false, false, true><<<dim3(3072 / 128, kM / 128), blk, 0, stream>>>(
        xnb, wbuf, nullptr, nullptr, nullptr, qkvb, 3072, 1024);
    transpV_k<<<dim3(kS / 64, 2, kB * kH), blk, 0, stream>>>(qkvb, vTb);
    attn_mfma_k<<<dim3(kS / 64, kH, kB), blk, 0, stream>>>(qkvb, vTb, aob);
    transp_k<<<dim3(32, 32, 1), blk, 0, stream>>>(w_attn_out, wbuf + 3 * M1, 1024, 1024, 0, 0);
    gemm_bf16_k<2, false, true, false, false><<<dim3(1024 / 64, kM / 128), blk, 0, stream>>>(
        aob, wbuf + 3 * M1, nullptr, nullptr, out, out, 1024, 1024);

    // ---- FFN: fused gate+up dual GEMM, then out proj ----
    rmsnorm_k<<<kM, blk, 0, stream>>>(out, rms_ffn, xnb);
    transp_k<<<dim3(128, 32, 1), blk, 0, stream>>>(w_ffn_gate, wbuf + 4 * M1, 1024, 4096, 0, 0);
    transp_k<<<dim3(128, 32, 1), blk, 0, stream>>>(w_ffn_up, wbuf + 8 * M1, 1024, 4096, 0, 0);
    gemm_bf16_k<4, false, false, true, true><<<dim3(4096 / 128, kM / 128), blk, 0, stream>>>(
        xnb, wbuf + 4 * M1, wbuf + 8 * M1, nullptr, nullptr, hidB, 4096, 1024);
    transp_k<<<dim3(32, 128, 1), blk, 0, stream>>>(w_ffn_out, wbuf, 4096, 1024, 0, 0);
    gemm_bf16_k<2, false, true, false, false><<<dim3(1024 / 64, kM / 128), blk, 0, stream>>>(
        hidB, wbuf, nullptr, nullptr, out, out, 1024, 4096);
}

// Round 5
// 638.032 us; speedup vs baseline: 5.3680x; 1.1382x over previous
//
#include <hip/hip_runtime.h>
#include <hip/hip_bf16.h>
#include <math.h>

// Problem constants
constexpr int kB   = 2;
constexpr int kS   = 2048;
constexpr int kD   = 1024;
constexpr int kFFN = 4096;
constexpr int kM   = kB * kS;      // 4096 tokens
constexpr int kH   = 8;
constexpr int kDH  = 128;
constexpr int kNC  = 64;           // scan chunks
constexpr int kT   = kS / kNC;     // 32 steps per chunk

typedef unsigned short u16;
typedef __attribute__((ext_vector_type(8))) short short8;
typedef __attribute__((ext_vector_type(4))) float f32x4;

__device__ __forceinline__ float sigf(float x) { return 1.0f / (1.0f + __expf(-x)); }
__device__ __forceinline__ float bu2f(u16 u) { return __uint_as_float(((unsigned)u) << 16); }
__device__ __forceinline__ u16 f2bu(float f) {
    __hip_bfloat16 h = __float2bfloat16(f);
    return reinterpret_cast<u16&>(h);
}
__device__ __forceinline__ void async16(const void* g, void* l) {
    __builtin_amdgcn_global_load_lds((const __attribute__((address_space(1))) void*)g,
                                     (__attribute__((address_space(3))) void*)l, 16, 0, 0);
}

// ---------------- RMSNorm: f32 in, bf16 out ---------------------------------
__global__ __launch_bounds__(256) void rmsnorm_k(const float* __restrict__ x,
                                                 const float* __restrict__ w,
                                                 u16* __restrict__ o)
{
    __shared__ float red[4];
    const int row = blockIdx.x;
    const int t = threadIdx.x;
    float4 v = ((const float4*)(x + (size_t)row * kD))[t];
    float ss = v.x*v.x + v.y*v.y + v.z*v.z + v.w*v.w;
    #pragma unroll
    for (int m = 32; m; m >>= 1) ss += __shfl_xor(ss, m);
    if ((t & 63) == 0) red[t >> 6] = ss;
    __syncthreads();
    float tot = red[0] + red[1] + red[2] + red[3];
    float r = rsqrtf(tot * (1.0f / (float)kD) + 1e-6f);
    float4 wv = ((const float4*)w)[t];
    ushort4 u;
    u.x = f2bu(v.x * r * wv.x); u.y = f2bu(v.y * r * wv.y);
    u.z = f2bu(v.z * r * wv.z); u.w = f2bu(v.w * r * wv.w);
    ((ushort4*)(o + (size_t)row * kD))[t] = u;
}

// ---------------- Routing: pure f32 from x (top-k must not see bf16) --------
__global__ __launch_bounds__(64) void routing_k(const float* __restrict__ x,
                                                const float* __restrict__ wmix,
                                                const float* __restrict__ gw,
                                                float* __restrict__ wts,
                                                int* __restrict__ idx)
{
    const int row = blockIdx.x;
    const int lane = threadIdx.x;
    const float* xr = x + (size_t)row * kD;
    float ss = 0.0f;
    for (int d = lane; d < kD; d += 64) { float v = xr[d]; ss = fmaf(v, v, ss); }
    #pragma unroll
    for (int m = 32; m; m >>= 1) ss += __shfl_xor(ss, m);
    float r = rsqrtf(ss * (1.0f / (float)kD) + 1e-6f);

    float a0 = 0, a1 = 0, a2 = 0, a3 = 0;
    for (int d = lane; d < kD; d += 64) {
        float xv = xr[d] * wmix[d];
        float4 g = ((const float4*)gw)[d];
        a0 = fmaf(xv, g.x, a0);
        a1 = fmaf(xv, g.y, a1);
        a2 = fmaf(xv, g.z, a2);
        a3 = fmaf(xv, g.w, a3);
    }
    #pragma unroll
    for (int m = 32; m; m >>= 1) {
        a0 += __shfl_xor(a0, m);
        a1 += __shfl_xor(a1, m);
        a2 += __shfl_xor(a2, m);
        a3 += __shfl_xor(a3, m);
    }
    if (lane == 0) {
        float a[4] = {a0, a1, a2, a3};
        int i0 = 0; float v0 = a[0];
        #pragma unroll
        for (int e = 1; e < 4; ++e) if (a[e] > v0) { v0 = a[e]; i0 = e; }
        int i1 = -1; float v1 = -INFINITY;
        #pragma unroll
        for (int e = 0; e < 4; ++e) if (e != i0 && a[e] > v1) { v1 = a[e]; i1 = e; }
        float e1 = __expf(r * (v1 - v0));
        float dn = 1.0f + e1;
        wts[row * 2 + 0] = 1.0f / dn;
        wts[row * 2 + 1] = e1 / dn;
        idx[row * 2 + 0] = i0;
        idx[row * 2 + 1] = i1;
    }
}

// ---------------- Transpose-convert: f32 [rows][cols] -> bf16 [cols][rows] --
__global__ __launch_bounds__(256) void transp_k(const float* __restrict__ src,
                                                u16* __restrict__ dst,
                                                int rows, int cols,
                                                size_t sstride, size_t dstride)
{
    __shared__ float t[32][33];
    const float* s = src + blockIdx.z * sstride;
    u16* d = dst + blockIdx.z * dstride;
    const int c0 = blockIdx.x * 32, r0 = blockIdx.y * 32;
    const int tc = threadIdx.x & 31, tr4 = (threadIdx.x >> 5) * 4;
    #pragma unroll
    for (int i = 0; i < 4; ++i)
        t[tr4 + i][tc] = s[(size_t)(r0 + tr4 + i) * cols + c0 + tc];
    __syncthreads();
    #pragma unroll
    for (int i = 0; i < 4; ++i) {
        int cc = tr4 + i;
        d[(size_t)(c0 + cc) * rows + r0 + tc] = f2bu(t[tc][cc]);
    }
}

// ---------------- Bias pack: [E][3072] = bg|bv|bd ---------------------------
__global__ __launch_bounds__(256) void biaspack_k(const float* __restrict__ bg,
                                                  const float* __restrict__ bv,
                                                  const float* __restrict__ bd,
                                                  float* __restrict__ pb)
{
    int e = blockIdx.y;
    int r = blockIdx.x * 256 + threadIdx.x;   // 0..3071
    const float* src = (r < 1024) ? bg : (r < 2048) ? bv : bd;
    pb[e * 3072 + r] = src[e * 1024 + (r & 1023)];
}

// ---------------- bf16 MFMA GEMM, 2-phase double-buffered --------------------
// C[M,N] = A[M,K] @ BT[N,K]^T.  BM=128, BN=32*WN, BK=32, 256 threads (4 waves 2x2).
// Schedule per iter: stage(next tile, buf^1) -> ds_read+MFMA(buf) -> barrier.
// Compiler drains vmcnt(0) before s_barrier => stage latency hides under MFMA.
template<int WN, bool BIAS, bool RES, bool SILU, bool MUL, bool OBF>
__global__ __launch_bounds__(256, 2) void gemm_bf16_k(
    const u16* __restrict__ A, const u16* __restrict__ BT,
    const float* __restrict__ bias, const float* __restrict__ res,
    const u16* __restrict__ mulsrc, void* __restrict__ Cout,
    int N, int K)
{
    constexpr int BN = 32 * WN;
    __shared__ __align__(16) u16 As[2][128 * 32];
    __shared__ __align__(16) u16 Bs[2][BN * 32];
    const int tid = threadIdx.x;
    const int lane = tid & 63;
    const int w = tid >> 6;
    const int wr = w >> 1, wc = w & 1;

    // bijective XCD-aware block swizzle (m204)
    const int gx = gridDim.x;
    const int nwg = gx * gridDim.y;
    const int orig = blockIdx.y * gx + blockIdx.x;
    const int xcd = orig & 7;
    const int q8 = nwg >> 3, r8 = nwg & 7;
    const int wg = (xcd < r8 ? xcd * (q8 + 1) : r8 * (q8 + 1) + (xcd - r8) * q8) + (orig >> 3);
    const int bm = (wg / gx) * 128, bn = (wg % gx) * BN;

    const int fr = lane & 15, fk = (lane >> 4) * 8;

    const u16* gA1 = A + (size_t)(bm + (tid >> 2)) * K + (tid & 3) * 8;
    const u16* gA2 = gA1 + (size_t)64 * K;
    const u16* gB1 = BT + (size_t)(bn + (tid >> 2)) * K + (tid & 3) * 8;
    const u16* gB2 = gB1 + (size_t)64 * K;

    f32x4 acc[4][WN];
    #pragma unroll
    for (int m = 0; m < 4; ++m)
        #pragma unroll
        for (int n = 0; n < WN; ++n) acc[m][n] = (f32x4){0.f, 0.f, 0.f, 0.f};

    const int paOff = (wr * 64 + fr) * 32 + fk;
    const int pbOff = (wc * WN * 16 + fr) * 32 + fk;

    // prologue: stage tile 0 into buf 0
    async16(gA1, As[0] + tid * 8);
    async16(gA2, As[0] + (256 + tid) * 8);
    async16(gB1, Bs[0] + tid * 8);
    if constexpr (WN == 4) async16(gB2, Bs[0] + (256 + tid) * 8);
    __syncthreads();

    int cur = 0;
    for (int k0 = 0; k0 < K; k0 += 32) {
        if (k0 + 32 < K) {       // stage next tile FIRST (overlaps with compute)
            const int nb = cur ^ 1;
            async16(gA1 + k0 + 32, As[nb] + tid * 8);
            async16(gA2 + k0 + 32, As[nb] + (256 + tid) * 8);
            async16(gB1 + k0 + 32, Bs[nb] + tid * 8);
            if constexpr (WN == 4) async16(gB2 + k0 + 32, Bs[nb] + (256 + tid) * 8);
        }
        const u16* pa = As[cur] + paOff;
        const u16* pb = Bs[cur] + pbOff;
        short8 a[4], b[WN];
        #pragma unroll
        for (int m = 0; m < 4; ++m) a[m] = *(const short8*)(pa + m * 512);
        #pragma unroll
        for (int n = 0; n < WN; ++n) b[n] = *(const short8*)(pb + n * 512);
        #pragma unroll
        for (int m = 0; m < 4; ++m)
            #pragma unroll
            for (int n = 0; n < WN; ++n)
                acc[m][n] = __builtin_amdgcn_mfma_f32_16x16x32_bf16(a[m], b[n], acc[m][n], 0, 0, 0);
        __syncthreads();         // drains vmcnt (next tile landed) + joins waves
        cur ^= 1;
    }

    const int orow0 = bm + wr * 64 + ((lane >> 4) << 2);
    const int ocol0 = bn + wc * WN * 16 + fr;
    float bi[WN];
    if constexpr (BIAS) {
        #pragma unroll
        for (int n = 0; n < WN; ++n) bi[n] = bias[ocol0 + n * 16];
    }
    #pragma unroll
    for (int m = 0; m < 4; ++m) {
        #pragma unroll
        for (int r = 0; r < 4; ++r) {
            const int row = orow0 + m * 16 + r;
            const size_t ro = (size_t)row * N;
            #pragma unroll
            for (int n = 0; n < WN; ++n) {
                const size_t off = ro + ocol0 + n * 16;
                float v = acc[m][n][r];
                if constexpr (BIAS) v += bi[n];
                if constexpr (SILU) v = v * sigf(v);
                if constexpr (MUL)  v *= bu2f(mulsrc[off]);
                if constexpr (RES)  v += res[off];
                if constexpr (OBF)  ((u16*)Cout)[off] = f2bu(v);
                else                ((float*)Cout)[off] = v;
            }
        }
    }
}

// ---------------- minGRU chunked scan; gvd bf16 [M][3072] = g|v|d ------------
__global__ __launch_bounds__(256) void scan1_k(const u16* __restrict__ gvd,
                                               float* __restrict__ sumA,
                                               float* __restrict__ sumX)
{
    int i = blockIdx.x * 256 + threadIdx.x;      // [0, kB*kNC*kD)
    int d = i & (kD - 1);
    int c = (i >> 10) & (kNC - 1);
    int b = i >> 16;
    size_t base = ((size_t)b * kS + c * kT) * 3072 + d;
    float A = 1.0f, X = 0.0f;
    for (int t = 0; t < kT; ++t) {
        size_t ix = base + (size_t)t * 3072;
        float xs = sigf(bu2f(gvd[ix])) * tanhf(bu2f(gvd[ix + 1024]));
        float a  = 0.001f + 0.998f * sigf(bu2f(gvd[ix + 2048]));
        A *= a;
        X = fmaf(a, X, xs);
    }
    sumA[c * (kB * kD) + b * kD + d] = A;
    sumX[c * (kB * kD) + b * kD + d] = X;
}

__global__ __launch_bounds__(256) void scan2_k(const float* __restrict__ sumA,
                                               const float* __restrict__ sumX,
                                               float* __restrict__ carry)
{
    int bd = blockIdx.x * 256 + threadIdx.x;     // [0, kB*kD)
    float h = 0.0f;
    for (int c = 0; c < kNC; ++c) {
        carry[c * (kB * kD) + bd] = h;
        h = fmaf(sumA[c * (kB * kD) + bd], h, sumX[c * (kB * kD) + bd]);
    }
}

__global__ __launch_bounds__(256) void scan3_k(const u16* __restrict__ gvd,
                                               const float* __restrict__ carry,
                                               u16* __restrict__ hout)
{
    int i = blockIdx.x * 256 + threadIdx.x;
    int d = i & (kD - 1);
    int c = (i >> 10) & (kNC - 1);
    int b = i >> 16;
    size_t base = ((size_t)b * kS + c * kT) * 3072 + d;
    size_t obase = ((size_t)b * kS + c * kT) * kD + d;
    float h = carry[c * (kB * kD) + b * kD + d];
    for (int t = 0; t < kT; ++t) {
        size_t ix = base + (size_t)t * 3072;
        float xs = sigf(bu2f(gvd[ix])) * tanhf(bu2f(gvd[ix + 1024]));
        float a  = 0.001f + 0.998f * sigf(bu2f(gvd[ix + 2048]));
        h = fmaf(a, h, xs);
        hout[obase + (size_t)t * kD] = f2bu(h);
    }
}

// ---------------- MoE mix: out = x + w0*eh[i0] + w1*eh[i1] (eh bf16) --------
__global__ __launch_bounds__(256) void mix_k(const float* __restrict__ x,
                                             const u16* __restrict__ ehb,
                                             const float* __restrict__ wts,
                                             const int* __restrict__ idx,
                                             float* __restrict__ xo)
{
    size_t i = (size_t)blockIdx.x * 256 + threadIdx.x;  // 4-elem group index
    int m = (int)(i >> 8);
    float w0 = wts[m * 2 + 0], w1 = wts[m * 2 + 1];
    int e0 = idx[m * 2 + 0], e1 = idx[m * 2 + 1];
    size_t MD4 = (size_t)kM * (kD / 4);
    float4 xv = ((const float4*)x)[i];
    ushort4 h0 = ((const ushort4*)ehb)[(size_t)e0 * MD4 + i];
    ushort4 h1 = ((const ushort4*)ehb)[(size_t)e1 * MD4 + i];
    float4 o;
    o.x = xv.x + w0 * bu2f(h0.x) + w1 * bu2f(h1.x);
    o.y = xv.y + w0 * bu2f(h0.y) + w1 * bu2f(h1.y);
    o.z = xv.z + w0 * bu2f(h0.z) + w1 * bu2f(h1.z);
    o.w = xv.w + w0 * bu2f(h0.w) + w1 * bu2f(h1.w);
    ((float4*)xo)[i] = o;
}

// ---------------- V transpose: qkvb V-part -> vT [b*H+h][128 d][2048 s] -----
__global__ __launch_bounds__(256) void transpV_k(const u16* __restrict__ qkvb,
                                                 u16* __restrict__ vT)
{
    __shared__ u16 t[64][68];
    const int tid = threadIdx.x;
    const int s0 = blockIdx.x * 64;
    const int d0 = blockIdx.y * 64;
    const int bh = blockIdx.z;
    const int bb = bh >> 3, hh = bh & 7;
    const u16* src = qkvb + (size_t)(bb * kS + s0) * 3072 + 2048 + hh * kDH + d0;
    for (int idx = tid; idx < 64 * 16; idx += 256) {
        int sl = idx >> 4, c4 = (idx & 15) * 4;
        *(ushort4*)&t[sl][c4] = *(const ushort4*)(src + (size_t)sl * 3072 + c4);
    }
    __syncthreads();
    u16* dst = vT + ((size_t)bh * kDH + d0) * kS + s0;
    for (int idx = tid; idx < 64 * 16; idx += 256) {
        int dl = idx >> 4, s4 = (idx & 15) * 4;
        ushort4 v;
        v.x = t[s4 + 0][dl]; v.y = t[s4 + 1][dl];
        v.z = t[s4 + 2][dl]; v.w = t[s4 + 3][dl];
        *(ushort4*)(dst + (size_t)dl * kS + s4) = v;
    }
}

// ---------------- MFMA sliding-window attention ------------------------------
// Block: (64-query tile, head, batch). 4 waves, 16 q each. Keys: 192 window.
__global__ __launch_bounds__(256) void attn_mfma_k(const u16* __restrict__ qkvb,
                                                   const u16* __restrict__ vT,
                                                   u16* __restrict__ aob)
{
    __shared__ __align__(16) u16 KV[26112];      // K: [192][136] | VT: [128][200]
    __shared__ __align__(16) u16 P[4 * 16 * 200];

    const int tid = threadIdx.x;
    const int lane = tid & 63;
    const int w = tid >> 6;
    const int fr = lane & 15, g = lane >> 4;
    const int q0 = blockIdx.x * 64;
    const int hh = blockIdx.y;
    const int bb = blockIdx.z;
    const int kbase = q0 - 128;
    const float scale = 0.08838834764831845f;    // 1/sqrt(128)

    const u16* qkv_b = qkvb + (size_t)bb * kS * 3072 + hh * kDH;

    // stage K [192][136]
    for (int idx = tid; idx < 192 * 16; idx += 256) {
        int k = idx >> 4, c = idx & 15;
        int kg = kbase + k; if (kg < 0) kg = 0;
        short8 v = *(const short8*)(qkv_b + (size_t)kg * 3072 + 1024 + c * 8);
        *(short8*)(&KV[k * 136 + c * 8]) = v;
    }
    // Q frags direct from global
    short8 qf[4];
    {
        const u16* qrow = qkv_b + (size_t)(q0 + w * 16 + fr) * 3072 + g * 8;
        #pragma unroll
        for (int s = 0; s < 4; ++s) qf[s] = *(const short8*)(qrow + s * 32);
    }
    __syncthreads();

    // QK^T
    f32x4 sacc[12];
    #pragma unroll
    for (int f = 0; f < 12; ++f) sacc[f] = (f32x4){0.f, 0.f, 0.f, 0.f};
    #pragma unroll
    for (int s = 0; s < 4; ++s) {
        #pragma unroll
        for (int f = 0; f < 12; ++f) {
            short8 bfr = *(const short8*)(&KV[(f * 16 + fr) * 136 + s * 32 + g * 8]);
            sacc[f] = __builtin_amdgcn_mfma_f32_16x16x32_bf16(qf[s], bfr, sacc[f], 0, 0, 0);
        }
    }

    // mask + softmax (rows lane-local per r)
    float p[12][4];
    #pragma unroll
    for (int r = 0; r < 4; ++r) {
        const int ql = w * 16 + g * 4 + r;
        int kmin = 128 - q0; if (kmin < ql + 1) kmin = ql + 1;
        const int kmax = ql + 128;
        float mx = -1e30f;
        #pragma unroll
        for (int f = 0; f < 12; ++f) {
            int kl = f * 16 + fr;
            float sv = (kl >= kmin && kl <= kmax) ? sacc[f][r] * scale : -1e30f;
            p[f][r] = sv;
            mx = fmaxf(mx, sv);
        }
        mx = fmaxf(mx, __shfl_xor(mx, 1));
        mx = fmaxf(mx, __shfl_xor(mx, 2));
        mx = fmaxf(mx, __shfl_xor(mx, 4));
        mx = fmaxf(mx, __shfl_xor(mx, 8));
        float l = 0.f;
        #pragma unroll
        for (int f = 0; f < 12; ++f) { float e = __expf(p[f][r] - mx); p[f][r] = e; l += e; }
        l += __shfl_xor(l, 1);
        l += __shfl_xor(l, 2);
        l += __shfl_xor(l, 4);
        l += __shfl_xor(l, 8);
        float linv = 1.0f / l;
        #pragma unroll
        for (int f = 0; f < 12; ++f) p[f][r] *= linv;
    }

    // write P (bf16, normalized) to LDS [wave][16 q][200 pitch]
    {
        u16* pw = &P[(w * 16) * 200];
        #pragma unroll
        for (int r = 0; r < 4; ++r)
            #pragma unroll
            for (int f = 0; f < 12; ++f)
                pw[(g * 4 + r) * 200 + f * 16 + fr] = f2bu(p[f][r]);
    }
    __syncthreads();

    // stage VT [128][200] over KV
    {
        const u16* vrow = vT + (size_t)(bb * kH + hh) * kDH * kS;
        for (int idx = tid; idx < 128 * 25; idx += 256) {
            int d = idx / 25, c = idx % 25;
            if (c < 24) {
                int s0k = kbase + c * 8;
                short8 v;
                if (s0k < 0) v = (short8){0, 0, 0, 0, 0, 0, 0, 0};
                else v = *(const short8*)(vrow + (size_t)d * kS + s0k);
                *(short8*)(&KV[d * 200 + c * 8]) = v;
            }
        }
    }
    __syncthreads();

    // PV
    f32x4 oacc[8];
    #pragma unroll
    for (int f = 0; f < 8; ++f) oacc[f] = (f32x4){0.f, 0.f, 0.f, 0.f};
    const u16* pr = &P[(w * 16 + fr) * 200 + g * 8];
    #pragma unroll
    for (int s = 0; s < 6; ++s) {
        short8 afr = *(const short8*)(pr + s * 32);
        #pragma unroll
        for (int f = 0; f < 8; ++f) {
            short8 bfr = *(const short8*)(&KV[(f * 16 + fr) * 200 + s * 32 + g * 8]);
            oacc[f] = __builtin_amdgcn_mfma_f32_16x16x32_bf16(afr, bfr, oacc[f], 0, 0, 0);
        }
    }
    u16* orow = aob + ((size_t)(bb * kS + q0 + w * 16 + g * 4) * kD) + hh * kDH + fr;
    #pragma unroll
    for (int r = 0; r < 4; ++r)
        #pragma unroll
        for (int f = 0; f < 8; ++f)
            orow[(size_t)r * kD + f * 16] = f2bu(oacc[f][r]);
}

// ---------------------------------------------------------------------------
extern "C" void kernel_launch(void* const* d_in, const int* in_sizes, int n_in,
                              void* d_out, int out_size, void* d_ws, size_t ws_size,
                              hipStream_t stream)
{
    (void)in_sizes; (void)n_in; (void)out_size; (void)ws_size;

    const float* x          = (const float*)d_in[0];
    const float* rms_mix    = (const float*)d_in[1];
    const float* gate_w     = (const float*)d_in[2];
    const float* Wg         = (const float*)d_in[3];
    const float* bg         = (const float*)d_in[4];
    const float* Wv         = (const float*)d_in[5];
    const float* bv         = (const float*)d_in[6];
    const float* Wd         = (const float*)d_in[7];
    const float* bd         = (const float*)d_in[8];
    const float* rms_attn   = (const float*)d_in[9];
    const float* w_qkv      = (const float*)d_in[10];
    const float* w_attn_out = (const float*)d_in[11];
    const float* rms_ffn    = (const float*)d_in[12];
    const float* w_ffn_gate = (const float*)d_in[13];
    const float* w_ffn_up   = (const float*)d_in[14];
    const float* w_ffn_out  = (const float*)d_in[15];
    float* out = (float*)d_out;

    const size_t MD = (size_t)kM * kD;
    const size_t M1 = 1024ull * 1024;   // u16 elements per 1024x1024 matrix
    char* p = (char*)d_ws;
    auto take = [&](size_t n) { char* r = p; p += (n + 255) & ~(size_t)255; return r; };

    u16*   xnb   = (u16*)take(MD * 2);                  // 8.4 MB
    u16*   arena = (u16*)take((size_t)kM * kFFN * 2);   // 33.6 MB: gvd | qkvb | hidB
    u16*   gvd   = arena;
    u16*   qkvb  = arena;
    u16*   hidB  = arena;
    u16*   ehb   = (u16*)take(4 * MD * 2);              // 33.6 MB: eh x4 | aob+vT | hidA
    u16*   aob   = ehb;
    u16*   vTb   = ehb + MD;
    u16*   hidA  = ehb;                                 // FFN phase reuse (2 x MD)
    u16*   wbuf  = (u16*)take(12ull * M1 * 2);          // 25.2 MB transposed weights
    float* pbias = (float*)take(4 * 3072 * 4);
    float* sumA  = (float*)take((size_t)kNC * kB * kD * 4);
    float* sumX  = (float*)take((size_t)kNC * kB * kD * 4);
    float* carry = (float*)take((size_t)kNC * kB * kD * 4);
    float* wts   = (float*)take((size_t)2 * kM * 4);
    int*   tidx  = (int*)take((size_t)2 * kM * 4);

    const dim3 blk(256);

    // ---- expert weight transposes (z-batched) + bias pack ----
    transp_k<<<dim3(32, 32, 4), blk, 0, stream>>>(Wg, wbuf, 1024, 1024,
                                                  (size_t)kD * kD, 3 * M1);
    transp_k<<<dim3(32, 32, 4), blk, 0, stream>>>(Wv, wbuf + M1, 1024, 1024,
                                                  (size_t)kD * kD, 3 * M1);
    transp_k<<<dim3(32, 32, 4), blk, 0, stream>>>(Wd, wbuf + 2 * M1, 1024, 1024,
                                                  (size_t)kD * kD, 3 * M1);
    biaspack_k<<<dim3(12, 4), blk, 0, stream>>>(bg, bv, bd, pbias);

    // ---- stage 1: rmsnorm + routing ----
    rmsnorm_k<<<kM, blk, 0, stream>>>(x, rms_mix, xnb);
    routing_k<<<kM, dim3(64), 0, stream>>>(x, rms_mix, gate_w, wts, tidx);

    // ---- experts ----
    const int scan_blocks = kB * kD * kNC / 256;
    for (int e = 0; e < 4; ++e) {
        gemm_bf16_k<4, true, false, false, false, true><<<dim3(3072 / 128, kM / 128), blk, 0, stream>>>(
            xnb, wbuf + (size_t)e * 3 * M1, pbias + e * 3072, nullptr, nullptr, gvd, 3072, 1024);
        scan1_k<<<scan_blocks, blk, 0, stream>>>(gvd, sumA, sumX);
        scan2_k<<<kB * kD / 256, blk, 0, stream>>>(sumA, sumX, carry);
        scan3_k<<<scan_blocks, blk, 0, stream>>>(gvd, carry, ehb + (size_t)e * MD);
    }

    // ---- MoE mix -> out (x1) ----
    mix_k<<<(int)(MD / 1024), blk, 0, stream>>>(x, ehb, wts, tidx, out);

    // ---- attention ----
    rmsnorm_k<<<kM, blk, 0, stream>>>(out, rms_attn, xnb);
    transp_k<<<dim3(96, 32, 1), blk, 0, stream>>>(w_qkv, wbuf, 1024, 3072, 0, 0);
    gemm_bf16_k<4, false, false, false, false, true><<<dim3(3072 / 128, kM / 128), blk, 0, stream>>>(
        xnb, wbuf, nullptr, nullptr, nullptr, qkvb, 3072, 1024);
    transpV_k<<<dim3(kS / 64, 2, kB * kH), blk, 0, stream>>>(qkvb, vTb);
    attn_mfma_k<<<dim3(kS / 64, kH, kB), blk, 0, stream>>>(qkvb, vTb, aob);
    transp_k<<<dim3(32, 32, 1), blk, 0, stream>>>(w_attn_out, wbuf + 3 * M1, 1024, 1024, 0, 0);
    gemm_bf16_k<2, false, true, false, false, false><<<dim3(1024 / 64, kM / 128), blk, 0, stream>>>(
        aob, wbuf + 3 * M1, nullptr, out, nullptr, out, 1024, 1024);

    // ---- FFN: gate (silu) -> hidA; up (mul hidA) -> hidB; out proj ----
    rmsnorm_k<<<kM, blk, 0, stream>>>(out, rms_ffn, xnb);
    transp_k<<<dim3(128, 32, 1), blk, 0, stream>>>(w_ffn_gate, wbuf + 4 * M1, 1024, 4096, 0, 0);
    transp_k<<<dim3(128, 32, 1), blk, 0, stream>>>(w_ffn_up, wbuf + 8 * M1, 1024, 4096, 0, 0);
    transp_k<<<dim3(32, 128, 1), blk, 0, stream>>>(w_ffn_out, wbuf, 4096, 1024, 0, 0);
    gemm_bf16_k<4, false, false, true, false, true><<<dim3(4096 / 128, kM / 128), blk, 0, stream>>>(
        xnb, wbuf + 4 * M1, nullptr, nullptr, nullptr, hidA, 4096, 1024);
    gemm_bf16_k<4, false, false, false, true, true><<<dim3(4096 / 128, kM / 128), blk, 0, stream>>>(
        xnb, wbuf + 8 * M1, nullptr, nullptr, hidA, hidB, 4096, 1024);
    gemm_bf16_k<2, false, true, false, false, false><<<dim3(1024 / 64, kM / 128), blk, 0, stream>>>(
        hidB, wbuf, nullptr, out, nullptr, out, 1024, 4096);
}

// Round 6
// 528.254 us; speedup vs baseline: 6.4835x; 1.2078x over previous
//
#include <hip/hip_runtime.h>
#include <hip/hip_bf16.h>
#include <math.h>

// Problem constants
constexpr int kB   = 2;
constexpr int kS   = 2048;
constexpr int kD   = 1024;
constexpr int kFFN = 4096;
constexpr int kM   = kB * kS;      // 4096 tokens
constexpr int kH   = 8;
constexpr int kDH  = 128;
constexpr int kNC  = 64;           // scan chunks
constexpr int kT   = kS / kNC;     // 32 steps per chunk
constexpr int kNE  = 12288;        // 4 experts x 3072 packed N

typedef unsigned short u16;
typedef __attribute__((ext_vector_type(8))) short short8;
typedef __attribute__((ext_vector_type(4))) float f32x4;

__device__ __forceinline__ float sigf(float x) { return 1.0f / (1.0f + __expf(-x)); }
__device__ __forceinline__ float bu2f(u16 u) { return __uint_as_float(((unsigned)u) << 16); }
__device__ __forceinline__ u16 f2bu(float f) {
    __hip_bfloat16 h = __float2bfloat16(f);
    return reinterpret_cast<u16&>(h);
}
__device__ __forceinline__ void async16(const void* g, void* l) {
    __builtin_amdgcn_global_load_lds((const __attribute__((address_space(1))) void*)g,
                                     (__attribute__((address_space(3))) void*)l, 16, 0, 0);
}

// ---------------- RMSNorm: f32 in, bf16 out ---------------------------------
__global__ __launch_bounds__(256) void rmsnorm_k(const float* __restrict__ x,
                                                 const float* __restrict__ w,
                                                 u16* __restrict__ o)
{
    __shared__ float red[4];
    const int row = blockIdx.x;
    const int t = threadIdx.x;
    float4 v = ((const float4*)(x + (size_t)row * kD))[t];
    float ss = v.x*v.x + v.y*v.y + v.z*v.z + v.w*v.w;
    #pragma unroll
    for (int m = 32; m; m >>= 1) ss += __shfl_xor(ss, m);
    if ((t & 63) == 0) red[t >> 6] = ss;
    __syncthreads();
    float tot = red[0] + red[1] + red[2] + red[3];
    float r = rsqrtf(tot * (1.0f / (float)kD) + 1e-6f);
    float4 wv = ((const float4*)w)[t];
    ushort4 u;
    u.x = f2bu(v.x * r * wv.x); u.y = f2bu(v.y * r * wv.y);
    u.z = f2bu(v.z * r * wv.z); u.w = f2bu(v.w * r * wv.w);
    ((ushort4*)(o + (size_t)row * kD))[t] = u;
}

// ---------------- Routing: pure f32 from x (top-k must not see bf16) --------
__global__ __launch_bounds__(64) void routing_k(const float* __restrict__ x,
                                                const float* __restrict__ wmix,
                                                const float* __restrict__ gw,
                                                float* __restrict__ wts,
                                                int* __restrict__ idx)
{
    const int row = blockIdx.x;
    const int lane = threadIdx.x;
    const float* xr = x + (size_t)row * kD;
    float ss = 0.0f;
    for (int d = lane; d < kD; d += 64) { float v = xr[d]; ss = fmaf(v, v, ss); }
    #pragma unroll
    for (int m = 32; m; m >>= 1) ss += __shfl_xor(ss, m);
    float r = rsqrtf(ss * (1.0f / (float)kD) + 1e-6f);

    float a0 = 0, a1 = 0, a2 = 0, a3 = 0;
    for (int d = lane; d < kD; d += 64) {
        float xv = xr[d] * wmix[d];
        float4 g = ((const float4*)gw)[d];
        a0 = fmaf(xv, g.x, a0);
        a1 = fmaf(xv, g.y, a1);
        a2 = fmaf(xv, g.z, a2);
        a3 = fmaf(xv, g.w, a3);
    }
    #pragma unroll
    for (int m = 32; m; m >>= 1) {
        a0 += __shfl_xor(a0, m);
        a1 += __shfl_xor(a1, m);
        a2 += __shfl_xor(a2, m);
        a3 += __shfl_xor(a3, m);
    }
    if (lane == 0) {
        float a[4] = {a0, a1, a2, a3};
        int i0 = 0; float v0 = a[0];
        #pragma unroll
        for (int e = 1; e < 4; ++e) if (a[e] > v0) { v0 = a[e]; i0 = e; }
        int i1 = -1; float v1 = -INFINITY;
        #pragma unroll
        for (int e = 0; e < 4; ++e) if (e != i0 && a[e] > v1) { v1 = a[e]; i1 = e; }
        float e1 = __expf(r * (v1 - v0));
        float dn = 1.0f + e1;
        wts[row * 2 + 0] = 1.0f / dn;
        wts[row * 2 + 1] = e1 / dn;
        idx[row * 2 + 0] = i0;
        idx[row * 2 + 1] = i1;
    }
}

// ---------------- Transpose-convert: f32 [rows][cols] -> bf16 [cols][rows] --
__global__ __launch_bounds__(256) void transp_k(const float* __restrict__ src,
                                                u16* __restrict__ dst,
                                                int rows, int cols,
                                                size_t sstride, size_t dstride)
{
    __shared__ float t[32][33];
    const float* s = src + blockIdx.z * sstride;
    u16* d = dst + blockIdx.z * dstride;
    const int c0 = blockIdx.x * 32, r0 = blockIdx.y * 32;
    const int tc = threadIdx.x & 31, tr4 = (threadIdx.x >> 5) * 4;
    #pragma unroll
    for (int i = 0; i < 4; ++i)
        t[tr4 + i][tc] = s[(size_t)(r0 + tr4 + i) * cols + c0 + tc];
    __syncthreads();
    #pragma unroll
    for (int i = 0; i < 4; ++i) {
        int cc = tr4 + i;
        d[(size_t)(c0 + cc) * rows + r0 + tc] = f2bu(t[tc][cc]);
    }
}

// ---------------- Bias pack: [12288] = e-major (bg|bv|bd) -------------------
__global__ __launch_bounds__(256) void biaspack_k(const float* __restrict__ bg,
                                                  const float* __restrict__ bv,
                                                  const float* __restrict__ bd,
                                                  float* __restrict__ pb)
{
    int e = blockIdx.y;
    int r = blockIdx.x * 256 + threadIdx.x;   // 0..3071
    const float* src = (r < 1024) ? bg : (r < 2048) ? bv : bd;
    pb[e * 3072 + r] = src[e * 1024 + (r & 1023)];
}

// ---------------- gemm256: BM=256 BN=128 BK=64, 8 waves, 3-stage pipeline ----
// C[M,N] = A[M,K] @ BT[N,K]^T, bf16 out. Counted vmcnt(6), raw s_barrier.
// LDS bank-conflict-free via chunk^=(row&7) swizzle applied to BOTH the
// global source address (linear global_load_lds dest) and the ds_read addr.
template<bool BIAS, bool SILU, bool MUL>
__global__ __launch_bounds__(512, 2) void gemm256_k(
    const u16* __restrict__ A, const u16* __restrict__ BT,
    const float* __restrict__ bias, const u16* __restrict__ mulsrc,
    u16* __restrict__ Cout, int N, int K)
{
    __shared__ __align__(16) u16 lds[3 * 24576];   // 3 stages x (A 32KB | B 16KB)
    const int tid = threadIdx.x;
    const int l = tid & 63;
    const int w = tid >> 6;                 // 0..7
    const int wr = w >> 1, wc = w & 1;      // 4M x 2N wave grid
    const int fr = l & 15, g = l >> 4;

    // bijective XCD swizzle (m204)
    const int gx = gridDim.x;
    const int nwg = gx * gridDim.y;
    const int orig = blockIdx.y * gx + blockIdx.x;
    const int xcd = orig & 7;
    const int q8 = nwg >> 3, r8 = nwg & 7;
    const int wg = (xcd < r8 ? xcd * (q8 + 1) : r8 * (q8 + 1) + (xcd - r8) * q8) + (orig >> 3);
    const int bm = (wg / gx) * 256, bn = (wg % gx) * 128;

    // staging geometry: each async16 covers 8 rows x 64 k-cols (1024B)
    const int srow = l >> 3;                // row within 8-row chunk
    const int scol = (l & 7) ^ srow;        // pre-swizzled source col-chunk
    const u16* gA = A  + (size_t)(bm + srow) * K + scol * 8;
    const u16* gB = BT + (size_t)(bn + srow) * K + scol * 8;

    auto STAGE = [&](int kt, int sb) {
        u16* dst = lds + sb * 24576 + l * 8;
        const int k0 = kt * 64;
        #pragma unroll
        for (int i = 0; i < 4; ++i) {       // A: 32 chunks / 8 waves
            int chunk = w * 4 + i;
            async16(gA + (size_t)chunk * 8 * K + k0, dst + chunk * 512);
        }
        #pragma unroll
        for (int i = 0; i < 2; ++i) {       // B: 16 chunks / 8 waves
            int chunk = w * 2 + i;
            async16(gB + (size_t)chunk * 8 * K + k0, dst + 16384 + chunk * 512);
        }
    };

    f32x4 acc[4][4];
    #pragma unroll
    for (int m = 0; m < 4; ++m)
        #pragma unroll
        for (int n = 0; n < 4; ++n) acc[m][n] = (f32x4){0.f, 0.f, 0.f, 0.f};

    STAGE(0, 0);
    STAGE(1, 1);
    const int nt = K >> 6;
    int cs = 0;
    for (int t = 0; t < nt; ++t) {
        // wait for buf[cs]'s own loads (oldest); stage(t+1) may stay in flight
        if (t + 1 < nt) asm volatile("s_waitcnt vmcnt(6)" ::: "memory");
        else            asm volatile("s_waitcnt vmcnt(0)" ::: "memory");
        __builtin_amdgcn_s_barrier();
        __builtin_amdgcn_sched_barrier(0);
        if (t + 2 < nt) {                   // issue next-next tile FIRST
            int ns = cs + 2; if (ns >= 3) ns -= 3;
            STAGE(t + 2, ns);
        }
        const u16* bA = lds + cs * 24576;
        const u16* bB = bA + 16384;
        #pragma unroll
        for (int ks = 0; ks < 2; ++ks) {
            short8 a[4], b[4];
            const int xo = ((ks * 4 + g) ^ (fr & 7)) * 8;
            #pragma unroll
            for (int m = 0; m < 4; ++m)
                a[m] = *(const short8*)(bA + (wr * 64 + m * 16 + fr) * 64 + xo);
            #pragma unroll
            for (int n = 0; n < 4; ++n)
                b[n] = *(const short8*)(bB + (wc * 64 + n * 16 + fr) * 64 + xo);
            #pragma unroll
            for (int m = 0; m < 4; ++m)
                #pragma unroll
                for (int n = 0; n < 4; ++n)
                    acc[m][n] = __builtin_amdgcn_mfma_f32_16x16x32_bf16(a[m], b[n], acc[m][n], 0, 0, 0);
        }
        cs = (cs == 2) ? 0 : cs + 1;
    }

    const int orow0 = bm + wr * 64 + g * 4;
    const int ocol0 = bn + wc * 64 + fr;
    float bi[4];
    if constexpr (BIAS) {
        #pragma unroll
        for (int n = 0; n < 4; ++n) bi[n] = bias[ocol0 + n * 16];
    }
    #pragma unroll
    for (int m = 0; m < 4; ++m) {
        #pragma unroll
        for (int r = 0; r < 4; ++r) {
            const size_t ro = (size_t)(orow0 + m * 16 + r) * N;
            #pragma unroll
            for (int n = 0; n < 4; ++n) {
                const size_t off = ro + ocol0 + n * 16;
                float v = acc[m][n][r];
                if constexpr (BIAS) v += bi[n];
                if constexpr (SILU) v = v * sigf(v);
                if constexpr (MUL)  v *= bu2f(mulsrc[off]);
                Cout[off] = f2bu(v);
            }
        }
    }
}

// ---------------- bf16 MFMA GEMM, 2-phase (kept for N=1024 shapes) ----------
template<int WN, bool BIAS, bool RES, bool SILU, bool MUL, bool OBF>
__global__ __launch_bounds__(256, 2) void gemm_bf16_k(
    const u16* __restrict__ A, const u16* __restrict__ BT,
    const float* __restrict__ bias, const float* __restrict__ res,
    const u16* __restrict__ mulsrc, void* __restrict__ Cout,
    int N, int K)
{
    constexpr int BN = 32 * WN;
    __shared__ __align__(16) u16 As[2][128 * 32];
    __shared__ __align__(16) u16 Bs[2][BN * 32];
    const int tid = threadIdx.x;
    const int lane = tid & 63;
    const int w = tid >> 6;
    const int wr = w >> 1, wc = w & 1;

    const int gx = gridDim.x;
    const int nwg = gx * gridDim.y;
    const int orig = blockIdx.y * gx + blockIdx.x;
    const int xcd = orig & 7;
    const int q8 = nwg >> 3, r8 = nwg & 7;
    const int wg = (xcd < r8 ? xcd * (q8 + 1) : r8 * (q8 + 1) + (xcd - r8) * q8) + (orig >> 3);
    const int bm = (wg / gx) * 128, bn = (wg % gx) * BN;

    const int fr = lane & 15, fk = (lane >> 4) * 8;

    const u16* gA1 = A + (size_t)(bm + (tid >> 2)) * K + (tid & 3) * 8;
    const u16* gA2 = gA1 + (size_t)64 * K;
    const u16* gB1 = BT + (size_t)(bn + (tid >> 2)) * K + (tid & 3) * 8;
    const u16* gB2 = gB1 + (size_t)64 * K;

    f32x4 acc[4][WN];
    #pragma unroll
    for (int m = 0; m < 4; ++m)
        #pragma unroll
        for (int n = 0; n < WN; ++n) acc[m][n] = (f32x4){0.f, 0.f, 0.f, 0.f};

    const int paOff = (wr * 64 + fr) * 32 + fk;
    const int pbOff = (wc * WN * 16 + fr) * 32 + fk;

    async16(gA1, As[0] + tid * 8);
    async16(gA2, As[0] + (256 + tid) * 8);
    async16(gB1, Bs[0] + tid * 8);
    if constexpr (WN == 4) async16(gB2, Bs[0] + (256 + tid) * 8);
    __syncthreads();

    int cur = 0;
    for (int k0 = 0; k0 < K; k0 += 32) {
        if (k0 + 32 < K) {
            const int nb = cur ^ 1;
            async16(gA1 + k0 + 32, As[nb] + tid * 8);
            async16(gA2 + k0 + 32, As[nb] + (256 + tid) * 8);
            async16(gB1 + k0 + 32, Bs[nb] + tid * 8);
            if constexpr (WN == 4) async16(gB2 + k0 + 32, Bs[nb] + (256 + tid) * 8);
        }
        const u16* pa = As[cur] + paOff;
        const u16* pb = Bs[cur] + pbOff;
        short8 a[4], b[WN];
        #pragma unroll
        for (int m = 0; m < 4; ++m) a[m] = *(const short8*)(pa + m * 512);
        #pragma unroll
        for (int n = 0; n < WN; ++n) b[n] = *(const short8*)(pb + n * 512);
        #pragma unroll
        for (int m = 0; m < 4; ++m)
            #pragma unroll
            for (int n = 0; n < WN; ++n)
                acc[m][n] = __builtin_amdgcn_mfma_f32_16x16x32_bf16(a[m], b[n], acc[m][n], 0, 0, 0);
        __syncthreads();
        cur ^= 1;
    }

    const int orow0 = bm + wr * 64 + ((lane >> 4) << 2);
    const int ocol0 = bn + wc * WN * 16 + fr;
    float bi[WN];
    if constexpr (BIAS) {
        #pragma unroll
        for (int n = 0; n < WN; ++n) bi[n] = bias[ocol0 + n * 16];
    }
    #pragma unroll
    for (int m = 0; m < 4; ++m) {
        #pragma unroll
        for (int r = 0; r < 4; ++r) {
            const int row = orow0 + m * 16 + r;
            const size_t ro = (size_t)row * N;
            #pragma unroll
            for (int n = 0; n < WN; ++n) {
                const size_t off = ro + ocol0 + n * 16;
                float v = acc[m][n][r];
                if constexpr (BIAS) v += bi[n];
                if constexpr (SILU) v = v * sigf(v);
                if constexpr (MUL)  v *= bu2f(mulsrc[off]);
                if constexpr (RES)  v += res[off];
                if constexpr (OBF)  ((u16*)Cout)[off] = f2bu(v);
                else                ((float*)Cout)[off] = v;
            }
        }
    }
}

// ---------------- minGRU chunked scan over gvdall [M][12288] ----------------
// expert e occupies cols [e*3072, e*3072+3072) = g|v|d
__global__ __launch_bounds__(256) void scan1_k(const u16* __restrict__ gvdall,
                                               float* __restrict__ sumA,
                                               float* __restrict__ sumX)
{
    const int e = blockIdx.y;
    int i = blockIdx.x * 256 + threadIdx.x;      // [0, kB*kNC*kD)
    int d = i & (kD - 1);
    int c = (i >> 10) & (kNC - 1);
    int b = i >> 16;
    const u16* gvd = gvdall + e * 3072;
    size_t base = ((size_t)b * kS + c * kT) * kNE + d;
    float A = 1.0f, X = 0.0f;
    for (int t = 0; t < kT; ++t) {
        size_t ix = base + (size_t)t * kNE;
        float xs = sigf(bu2f(gvd[ix])) * tanhf(bu2f(gvd[ix + 1024]));
        float a  = 0.001f + 0.998f * sigf(bu2f(gvd[ix + 2048]));
        A *= a;
        X = fmaf(a, X, xs);
    }
    size_t si = ((size_t)(e * kNC + c) * kB + b) * kD + d;
    sumA[si] = A;
    sumX[si] = X;
}

__global__ __launch_bounds__(256) void scan2_k(const float* __restrict__ sumA,
                                               const float* __restrict__ sumX,
                                               float* __restrict__ carry)
{
    const int e = blockIdx.y;
    int bd = blockIdx.x * 256 + threadIdx.x;     // [0, kB*kD)
    float h = 0.0f;
    for (int c = 0; c < kNC; ++c) {
        size_t si = ((size_t)(e * kNC + c)) * (kB * kD) + bd;
        carry[si] = h;
        h = fmaf(sumA[si], h, sumX[si]);
    }
}

__global__ __launch_bounds__(256) void scan3_k(const u16* __restrict__ gvdall,
                                               const float* __restrict__ carry,
                                               u16* __restrict__ ehb)
{
    const int e = blockIdx.y;
    int i = blockIdx.x * 256 + threadIdx.x;
    int d = i & (kD - 1);
    int c = (i >> 10) & (kNC - 1);
    int b = i >> 16;
    const u16* gvd = gvdall + e * 3072;
    size_t base = ((size_t)b * kS + c * kT) * kNE + d;
    size_t obase = (size_t)e * kM * kD + ((size_t)b * kS + c * kT) * kD + d;
    float h = carry[((size_t)(e * kNC + c) * kB + b) * kD + d];
    for (int t = 0; t < kT; ++t) {
        size_t ix = base + (size_t)t * kNE;
        float xs = sigf(bu2f(gvd[ix])) * tanhf(bu2f(gvd[ix + 1024]));
        float a  = 0.001f + 0.998f * sigf(bu2f(gvd[ix + 2048]));
        h = fmaf(a, h, xs);
        ehb[obase + (size_t)t * kD] = f2bu(h);
    }
}

// ---------------- MoE mix: out = x + w0*eh[i0] + w1*eh[i1] (eh bf16) --------
__global__ __launch_bounds__(256) void mix_k(const float* __restrict__ x,
                                             const u16* __restrict__ ehb,
                                             const float* __restrict__ wts,
                                             const int* __restrict__ idx,
                                             float* __restrict__ xo)
{
    size_t i = (size_t)blockIdx.x * 256 + threadIdx.x;  // 4-elem group index
    int m = (int)(i >> 8);
    float w0 = wts[m * 2 + 0], w1 = wts[m * 2 + 1];
    int e0 = idx[m * 2 + 0], e1 = idx[m * 2 + 1];
    size_t MD4 = (size_t)kM * (kD / 4);
    float4 xv = ((const float4*)x)[i];
    ushort4 h0 = ((const ushort4*)ehb)[(size_t)e0 * MD4 + i];
    ushort4 h1 = ((const ushort4*)ehb)[(size_t)e1 * MD4 + i];
    float4 o;
    o.x = xv.x + w0 * bu2f(h0.x) + w1 * bu2f(h1.x);
    o.y = xv.y + w0 * bu2f(h0.y) + w1 * bu2f(h1.y);
    o.z = xv.z + w0 * bu2f(h0.z) + w1 * bu2f(h1.z);
    o.w = xv.w + w0 * bu2f(h0.w) + w1 * bu2f(h1.w);
    ((float4*)xo)[i] = o;
}

// ---------------- V transpose: qkvb V-part -> vT [b*H+h][128 d][2048 s] -----
__global__ __launch_bounds__(256) void transpV_k(const u16* __restrict__ qkvb,
                                                 u16* __restrict__ vT)
{
    __shared__ u16 t[64][68];
    const int tid = threadIdx.x;
    const int s0 = blockIdx.x * 64;
    const int d0 = blockIdx.y * 64;
    const int bh = blockIdx.z;
    const int bb = bh >> 3, hh = bh & 7;
    const u16* src = qkvb + (size_t)(bb * kS + s0) * 3072 + 2048 + hh * kDH + d0;
    for (int idx = tid; idx < 64 * 16; idx += 256) {
        int sl = idx >> 4, c4 = (idx & 15) * 4;
        *(ushort4*)&t[sl][c4] = *(const ushort4*)(src + (size_t)sl * 3072 + c4);
    }
    __syncthreads();
    u16* dst = vT + ((size_t)bh * kDH + d0) * kS + s0;
    for (int idx = tid; idx < 64 * 16; idx += 256) {
        int dl = idx >> 4, s4 = (idx & 15) * 4;
        ushort4 v;
        v.x = t[s4 + 0][dl]; v.y = t[s4 + 1][dl];
        v.z = t[s4 + 2][dl]; v.w = t[s4 + 3][dl];
        *(ushort4*)(dst + (size_t)dl * kS + s4) = v;
    }
}

// ---------------- MFMA sliding-window attention ------------------------------
__global__ __launch_bounds__(256) void attn_mfma_k(const u16* __restrict__ qkvb,
                                                   const u16* __restrict__ vT,
                                                   u16* __restrict__ aob)
{
    __shared__ __align__(16) u16 KV[26112];      // K: [192][136] | VT: [128][200]
    __shared__ __align__(16) u16 P[4 * 16 * 200];

    const int tid = threadIdx.x;
    const int lane = tid & 63;
    const int w = tid >> 6;
    const int fr = lane & 15, g = lane >> 4;
    const int q0 = blockIdx.x * 64;
    const int hh = blockIdx.y;
    const int bb = blockIdx.z;
    const int kbase = q0 - 128;
    const float scale = 0.08838834764831845f;    // 1/sqrt(128)

    const u16* qkv_b = qkvb + (size_t)bb * kS * 3072 + hh * kDH;

    for (int idx = tid; idx < 192 * 16; idx += 256) {
        int k = idx >> 4, c = idx & 15;
        int kg = kbase + k; if (kg < 0) kg = 0;
        short8 v = *(const short8*)(qkv_b + (size_t)kg * 3072 + 1024 + c * 8);
        *(short8*)(&KV[k * 136 + c * 8]) = v;
    }
    short8 qf[4];
    {
        const u16* qrow = qkv_b + (size_t)(q0 + w * 16 + fr) * 3072 + g * 8;
        #pragma unroll
        for (int s = 0; s < 4; ++s) qf[s] = *(const short8*)(qrow + s * 32);
    }
    __syncthreads();

    f32x4 sacc[12];
    #pragma unroll
    for (int f = 0; f < 12; ++f) sacc[f] = (f32x4){0.f, 0.f, 0.f, 0.f};
    #pragma unroll
    for (int s = 0; s < 4; ++s) {
        #pragma unroll
        for (int f = 0; f < 12; ++f) {
            short8 bfr = *(const short8*)(&KV[(f * 16 + fr) * 136 + s * 32 + g * 8]);
            sacc[f] = __builtin_amdgcn_mfma_f32_16x16x32_bf16(qf[s], bfr, sacc[f], 0, 0, 0);
        }
    }

    float p[12][4];
    #pragma unroll
    for (int r = 0; r < 4; ++r) {
        const int ql = w * 16 + g * 4 + r;
        int kmin = 128 - q0; if (kmin < ql + 1) kmin = ql + 1;
        const int kmax = ql + 128;
        float mx = -1e30f;
        #pragma unroll
        for (int f = 0; f < 12; ++f) {
            int kl = f * 16 + fr;
            float sv = (kl >= kmin && kl <= kmax) ? sacc[f][r] * scale : -1e30f;
            p[f][r] = sv;
            mx = fmaxf(mx, sv);
        }
        mx = fmaxf(mx, __shfl_xor(mx, 1));
        mx = fmaxf(mx, __shfl_xor(mx, 2));
        mx = fmaxf(mx, __shfl_xor(mx, 4));
        mx = fmaxf(mx, __shfl_xor(mx, 8));
        float l = 0.f;
        #pragma unroll
        for (int f = 0; f < 12; ++f) { float e = __expf(p[f][r] - mx); p[f][r] = e; l += e; }
        l += __shfl_xor(l, 1);
        l += __shfl_xor(l, 2);
        l += __shfl_xor(l, 4);
        l += __shfl_xor(l, 8);
        float linv = 1.0f / l;
        #pragma unroll
        for (int f = 0; f < 12; ++f) p[f][r] *= linv;
    }

    {
        u16* pw = &P[(w * 16) * 200];
        #pragma unroll
        for (int r = 0; r < 4; ++r)
            #pragma unroll
            for (int f = 0; f < 12; ++f)
                pw[(g * 4 + r) * 200 + f * 16 + fr] = f2bu(p[f][r]);
    }
    __syncthreads();

    {
        const u16* vrow = vT + (size_t)(bb * kH + hh) * kDH * kS;
        for (int idx = tid; idx < 128 * 25; idx += 256) {
            int d = idx / 25, c = idx % 25;
            if (c < 24) {
                int s0k = kbase + c * 8;
                short8 v;
                if (s0k < 0) v = (short8){0, 0, 0, 0, 0, 0, 0, 0};
                else v = *(const short8*)(vrow + (size_t)d * kS + s0k);
                *(short8*)(&KV[d * 200 + c * 8]) = v;
            }
        }
    }
    __syncthreads();

    f32x4 oacc[8];
    #pragma unroll
    for (int f = 0; f < 8; ++f) oacc[f] = (f32x4){0.f, 0.f, 0.f, 0.f};
    const u16* pr = &P[(w * 16 + fr) * 200 + g * 8];
    #pragma unroll
    for (int s = 0; s < 6; ++s) {
        short8 afr = *(const short8*)(pr + s * 32);
        #pragma unroll
        for (int f = 0; f < 8; ++f) {
            short8 bfr = *(const short8*)(&KV[(f * 16 + fr) * 200 + s * 32 + g * 8]);
            oacc[f] = __builtin_amdgcn_mfma_f32_16x16x32_bf16(afr, bfr, oacc[f], 0, 0, 0);
        }
    }
    u16* orow = aob + ((size_t)(bb * kS + q0 + w * 16 + g * 4) * kD) + hh * kDH + fr;
    #pragma unroll
    for (int r = 0; r < 4; ++r)
        #pragma unroll
        for (int f = 0; f < 8; ++f)
            orow[(size_t)r * kD + f * 16] = f2bu(oacc[f][r]);
}

// ---------------------------------------------------------------------------
extern "C" void kernel_launch(void* const* d_in, const int* in_sizes, int n_in,
                              void* d_out, int out_size, void* d_ws, size_t ws_size,
                              hipStream_t stream)
{
    (void)in_sizes; (void)n_in; (void)out_size; (void)ws_size;

    const float* x          = (const float*)d_in[0];
    const float* rms_mix    = (const float*)d_in[1];
    const float* gate_w     = (const float*)d_in[2];
    const float* Wg         = (const float*)d_in[3];
    const float* bg         = (const float*)d_in[4];
    const float* Wv         = (const float*)d_in[5];
    const float* bv         = (const float*)d_in[6];
    const float* Wd         = (const float*)d_in[7];
    const float* bd         = (const float*)d_in[8];
    const float* rms_attn   = (const float*)d_in[9];
    const float* w_qkv      = (const float*)d_in[10];
    const float* w_attn_out = (const float*)d_in[11];
    const float* rms_ffn    = (const float*)d_in[12];
    const float* w_ffn_gate = (const float*)d_in[13];
    const float* w_ffn_up   = (const float*)d_in[14];
    const float* w_ffn_out  = (const float*)d_in[15];
    float* out = (float*)d_out;

    const size_t MD = (size_t)kM * kD;
    const size_t M1 = 1024ull * 1024;
    char* p = (char*)d_ws;
    auto take = [&](size_t n) { char* r = p; p += (n + 255) & ~(size_t)255; return r; };

    // ~174 MB total (R2 ran ~191 MB successfully)
    u16*   xnb    = (u16*)take(MD * 2);                     // 8.4 MB
    u16*   gvdall = (u16*)take((size_t)kM * kNE * 2);       // 100.7 MB: gvd | qkvb/hidA | hidB
    u16*   qkvb   = gvdall;
    u16*   hidA   = gvdall;
    u16*   hidB   = gvdall + (size_t)kM * kFFN;
    u16*   ehb    = (u16*)take(4 * MD * 2);                 // 33.6 MB: eh x4 | aob+vT
    u16*   aob    = ehb;
    u16*   vTb    = ehb + MD;
    u16*   wbuf   = (u16*)take(12ull * M1 * 2);             // 25.2 MB transposed weights
    float* pbias  = (float*)take((size_t)kNE * 4);
    float* sumA   = (float*)take(4ull * kNC * kB * kD * 4); // 2 MB each
    float* sumX   = (float*)take(4ull * kNC * kB * kD * 4);
    float* carry  = (float*)take(4ull * kNC * kB * kD * 4);
    float* wts    = (float*)take((size_t)2 * kM * 4);
    int*   tidx   = (int*)take((size_t)2 * kM * 4);

    const dim3 blk(256);

    // ---- expert weight transposes (wbuf = BT[12288][1024]) + bias pack ----
    transp_k<<<dim3(32, 32, 4), blk, 0, stream>>>(Wg, wbuf, 1024, 1024,
                                                  (size_t)kD * kD, 3 * M1);
    transp_k<<<dim3(32, 32, 4), blk, 0, stream>>>(Wv, wbuf + M1, 1024, 1024,
                                                  (size_t)kD * kD, 3 * M1);
    transp_k<<<dim3(32, 32, 4), blk, 0, stream>>>(Wd, wbuf + 2 * M1, 1024, 1024,
                                                  (size_t)kD * kD, 3 * M1);
    biaspack_k<<<dim3(12, 4), blk, 0, stream>>>(bg, bv, bd, pbias);

    // ---- stage 1: rmsnorm + routing ----
    rmsnorm_k<<<kM, blk, 0, stream>>>(x, rms_mix, xnb);
    routing_k<<<kM, dim3(64), 0, stream>>>(x, rms_mix, gate_w, wts, tidx);

    // ---- experts: ONE batched GEMM (N=12288) + z-batched scans ----
    gemm256_k<true, false, false><<<dim3(kNE / 128, kM / 256), dim3(512), 0, stream>>>(
        xnb, wbuf, pbias, nullptr, gvdall, kNE, 1024);
    const int scan_blocks = kB * kD * kNC / 256;
    scan1_k<<<dim3(scan_blocks, 4), blk, 0, stream>>>(gvdall, sumA, sumX);
    scan2_k<<<dim3(kB * kD / 256, 4), blk, 0, stream>>>(sumA, sumX, carry);
    scan3_k<<<dim3(scan_blocks, 4), blk, 0, stream>>>(gvdall, carry, ehb);

    // ---- MoE mix -> out (x1) ----
    mix_k<<<(int)(MD / 1024), blk, 0, stream>>>(x, ehb, wts, tidx, out);

    // ---- attention ----
    rmsnorm_k<<<kM, blk, 0, stream>>>(out, rms_attn, xnb);
    transp_k<<<dim3(96, 32, 1), blk, 0, stream>>>(w_qkv, wbuf, 1024, 3072, 0, 0);
    gemm256_k<false, false, false><<<dim3(3072 / 128, kM / 256), dim3(512), 0, stream>>>(
        xnb, wbuf, nullptr, nullptr, qkvb, 3072, 1024);
    transpV_k<<<dim3(kS / 64, 2, kB * kH), blk, 0, stream>>>(qkvb, vTb);
    attn_mfma_k<<<dim3(kS / 64, kH, kB), blk, 0, stream>>>(qkvb, vTb, aob);
    transp_k<<<dim3(32, 32, 1), blk, 0, stream>>>(w_attn_out, wbuf + 3 * M1, 1024, 1024, 0, 0);
    gemm_bf16_k<2, false, true, false, false, false><<<dim3(1024 / 64, kM / 128), blk, 0, stream>>>(
        aob, wbuf + 3 * M1, nullptr, out, nullptr, out, 1024, 1024);

    // ---- FFN ----
    rmsnorm_k<<<kM, blk, 0, stream>>>(out, rms_ffn, xnb);
    transp_k<<<dim3(128, 32, 1), blk, 0, stream>>>(w_ffn_gate, wbuf + 4 * M1, 1024, 4096, 0, 0);
    transp_k<<<dim3(128, 32, 1), blk, 0, stream>>>(w_ffn_up, wbuf + 8 * M1, 1024, 4096, 0, 0);
    transp_k<<<dim3(32, 128, 1), blk, 0, stream>>>(w_ffn_out, wbuf, 4096, 1024, 0, 0);
    gemm256_k<false, true, false><<<dim3(kFFN / 128, kM / 256), dim3(512), 0, stream>>>(
        xnb, wbuf + 4 * M1, nullptr, nullptr, hidA, kFFN, 1024);
    gemm256_k<false, false, true><<<dim3(kFFN / 128, kM / 256), dim3(512), 0, stream>>>(
        xnb, wbuf + 8 * M1, nullptr, hidA, hidB, kFFN, 1024);
    gemm_bf16_k<2, false, true, false, false, false><<<dim3(1024 / 64, kM / 128), blk, 0, stream>>>(
        hidB, wbuf, nullptr, out, nullptr, out, 1024, 4096);
}